// Round 6
// baseline (327.689 us; speedup 1.0000x reference)
//
#include <hip/hip_runtime.h>
#include <stdint.h>

typedef uint16_t u16;
typedef __attribute__((ext_vector_type(8))) short bf16x8;
typedef __attribute__((ext_vector_type(4))) float f32x4;

__device__ inline u16 f2b(float f) {          // fp32 -> bf16 RNE
  uint32_t u = __float_as_uint(f);
  u += 0x7FFF + ((u >> 16) & 1);
  return (u16)(u >> 16);
}
__device__ inline float b2f(u16 h) {          // bf16 -> fp32 exact
  return __uint_as_float(((uint32_t)h) << 16);
}

// Async global->LDS DMA, 16B per lane.
typedef __attribute__((address_space(1))) void gvoid;
typedef __attribute__((address_space(3))) void lvoid;
#define GLOAD16(gp, lp)                                                        \
  __builtin_amdgcn_global_load_lds((gvoid*)(gp), (lvoid*)(lp), 16, 0, 0)

// ---------------------------------------------------------------------------
// Inline dtype probe: mode 0 = bf16, 1 = fp32 (R4-proven).
// ---------------------------------------------------------------------------
__device__ __forceinline__ int probe_mode(const u16* __restrict__ P, int t,
                                          int* cnt_sh) {
  if (t == 0) *cnt_sh = 0;
  __syncthreads();
  float av = fabsf(b2f(P[t * 2]));
  if (av >= 1000.0f) atomicAdd(cnt_sh, 1);
  __syncthreads();
  return (*cnt_sh > 16) ? 1 : 0;
}

// ---------------------------------------------------------------------------
// Kernel 1: qkv = x @ w_qkv^T + RoPE/V-transpose. REBUILT on the m97
// structure (874 TF measured on this chip): grid (e, n128, m128) = 768
// blocks (3/CU), per block a 128x128xK GEMM, BK=32, single-buffered LDS
// staged by global_load_lds (linear dest, granule-XOR pre-swizzled global
// source + matching swizzled ds_read — rule #21), 2 plain barriers/step.
// 4 waves each own a 64x64 quadrant (acc[4][4] of 16x16).
// RoPE is register-local: pair (dh, dh^32) = acc[mt][nt^2] — no LDS, no
// barriers for Q/K. V keeps a 4-phase Cs transpose (unioned over staging).
// ---------------------------------------------------------------------------
__global__ __launch_bounds__(256) void k_qkv_rope(const void* __restrict__ Xv,
                                                  const void* __restrict__ Wv,
                                                  u16* __restrict__ Qo,
                                                  u16* __restrict__ Ko,
                                                  u16* __restrict__ Vo) {
  union Sh {
    struct { u16 A[128][32]; u16 B[128][32]; } st;   // 16 KB staging
    float Cs[64][66];                                 // V-transpose scratch
  };
  __shared__ Sh sh;
  __shared__ int cnt_sh;
  const int t = threadIdx.x, w = t >> 6, lane = t & 63;
  const int mode = probe_mode((const u16*)Xv, t, &cnt_sh);
  const int e  = blockIdx.x >> 3;         // 0=q 1=k 2=v
  const int nb = blockIdx.x & 7;          // n-tile 0..7
  const int n0 = nb * 128;                // spans heads 2*nb, 2*nb+1
  const int m0 = blockIdx.y * 128;
  const int lr = lane & 15, lq = lane >> 4;
  const int wm = w >> 1, wn = w & 1;      // wave's 64x64 quadrant
  f32x4 acc[4][4] = {};                   // [mt][nt]

  if (mode == 0) {
    const u16* Xp = (const u16*)Xv;
    const u16* Wp = (const u16*)Wv;
    // staging geometry: wave w stages rows [w*32, w*32+32) of A and B.
    // gload_lds writes LDS linearly (base + lane*16B): lane l -> row l>>2,
    // granule l&3. Source granule pre-swizzled: (l&3) ^ (row&3).
    const int lrow = lane >> 2;                    // 0..15 within 16-row group
    const int lg   = (lane & 3) ^ (lrow & 3);      // pre-swizzled granule
    const int arow = m0 + w * 32 + lrow;
    const int brow = e * 1024 + n0 + w * 32 + lrow;
    const u16* asrc0 = Xp + (long)arow * 1024 + lg * 8;
    const u16* asrc1 = Xp + (long)(arow + 16) * 1024 + lg * 8;
    const u16* bsrc0 = Wp + (long)brow * 1024 + lg * 8;
    const u16* bsrc1 = Wp + (long)(brow + 16) * 1024 + lg * 8;
    u16* ad0 = &sh.st.A[w * 32][0];
    u16* ad1 = &sh.st.A[w * 32 + 16][0];
    u16* bd0 = &sh.st.B[w * 32][0];
    u16* bd1 = &sh.st.B[w * 32 + 16][0];
    for (int k0 = 0; k0 < 1024; k0 += 32) {
      __syncthreads();                    // prior step's frag reads done
      GLOAD16(asrc0 + k0, ad0);
      GLOAD16(asrc1 + k0, ad1);
      GLOAD16(bsrc0 + k0, bd0);
      GLOAD16(bsrc1 + k0, bd1);
      __syncthreads();                    // drains vmcnt(0): tile resident
      bf16x8 af[4], bf[4];
#pragma unroll
      for (int x = 0; x < 4; ++x) {       // swizzled frag reads (row&3 = lr&3)
        const int ra = wm * 64 + x * 16 + lr;
        const int rb = wn * 64 + x * 16 + lr;
        af[x] = *(const bf16x8*)&sh.st.A[ra][(lq ^ (lr & 3)) * 8];
        bf[x] = *(const bf16x8*)&sh.st.B[rb][(lq ^ (lr & 3)) * 8];
      }
#pragma unroll
      for (int mt = 0; mt < 4; ++mt)
#pragma unroll
        for (int nt = 0; nt < 4; ++nt)
          acc[mt][nt] = __builtin_amdgcn_mfma_f32_16x16x32_bf16(af[mt], bf[nt], acc[mt][nt], 0, 0, 0);
    }
  } else {
    // fp32 fallback (dead in practice): reg-stage + convert, no swizzle
    const float* Xf = (const float*)Xv;
    const float* Wf = (const float*)Wv;
    const int r = t >> 1, ch = (t & 1) * 16;
    for (int k0 = 0; k0 < 1024; k0 += 32) {
      __syncthreads();
#pragma unroll
      for (int j = 0; j < 16; ++j) {
        sh.st.A[r][ch + j] = f2b(Xf[(long)(m0 + r) * 1024 + k0 + ch + j]);
        sh.st.B[r][ch + j] = f2b(Wf[(long)(e * 1024 + n0 + r) * 1024 + k0 + ch + j]);
      }
      __syncthreads();
      bf16x8 af[4], bf[4];
#pragma unroll
      for (int x = 0; x < 4; ++x) {
        af[x] = *(const bf16x8*)&sh.st.A[wm * 64 + x * 16 + lr][lq * 8];
        bf[x] = *(const bf16x8*)&sh.st.B[wn * 64 + x * 16 + lr][lq * 8];
      }
#pragma unroll
      for (int mt = 0; mt < 4; ++mt)
#pragma unroll
        for (int nt = 0; nt < 4; ++nt)
          acc[mt][nt] = __builtin_amdgcn_mfma_f32_16x16x32_bf16(af[mt], bf[nt], acc[mt][nt], 0, 0, 0);
    }
  }

  if (e < 2) {
    // ---- Q/K epilogue: RoPE fully in registers (pair = acc[mt][nt^2]) ----
    u16* O = (e == 0) ? Qo : Ko;
    const float fr0 = __expf((float)lr * -0.28782314f);          // dh&31 = lr
    const float fr1 = __expf((float)(16 + lr) * -0.28782314f);   // dh&31 = 16+lr
#pragma unroll
    for (int mt = 0; mt < 4; ++mt)
#pragma unroll
      for (int i = 0; i < 4; ++i) {
        const int m = m0 + wm * 64 + mt * 16 + lq * 4 + i;
        const int b = m >> 11, s = m & 2047;
        float sn0, cs0, sn1, cs1;
        __sincosf((float)s * fr0, &sn0, &cs0);
        __sincosf((float)s * fr1, &sn1, &cs1);
#pragma unroll
        for (int nt = 0; nt < 4; ++nt) {
          const int ng = n0 + wn * 64 + nt * 16 + lr;
          const int h = ng >> 6, dh = ng & 63;
          const float v  = acc[mt][nt][i];
          const float vp = acc[mt][nt ^ 2][i];      // partner dh^32
          const float sn = (nt & 1) ? sn1 : sn0;
          const float cs = (nt & 1) ? cs1 : cs0;
          const float sign = (dh < 32) ? -1.0f : 1.0f;
          O[((long)(b * 16 + h) * 2048 + s) * 64 + dh] = f2b(v * cs + sign * vp * sn);
        }
      }
  } else {
    // ---- V epilogue: 4-phase 64x64 transpose through Cs (unioned) ----
#pragma unroll 1
    for (int q = 0; q < 4; ++q) {
      const int qm = q >> 1, qn = q & 1;
      __syncthreads();                    // Cs free (staging reads / prior phase done)
      if (wm == qm && wn == qn) {
#pragma unroll
        for (int mt = 0; mt < 4; ++mt)
#pragma unroll
          for (int i = 0; i < 4; ++i)
#pragma unroll
            for (int nt = 0; nt < 4; ++nt)
              sh.Cs[mt * 16 + lq * 4 + i][nt * 16 + lr] = acc[mt][nt][i];
      }
      __syncthreads();
      const int sx = t & 63, dh0 = (t >> 6) * 16;
      const int mlin = m0 + qm * 64 + sx;
      const int b = mlin >> 11, s = mlin & 2047;
#pragma unroll
      for (int u = 0; u < 16; ++u) {
        const int dl = dh0 + u;
        const int ng = n0 + qn * 64 + dl;
        const int h = ng >> 6, dh = ng & 63;
        Vo[((long)(b * 16 + h) * 64 + dh) * 2048 + s] = f2b(sh.Cs[sx][dl]);
      }
    }
  }
}

// ---------------------------------------------------------------------------
// Per-tile attention body (R9-proven math, factored; per-tile qt/state).
// ---------------------------------------------------------------------------
__device__ __forceinline__ void attn_tile(u16 QP[64][72], u16 Ks[64][72],
                                          u16 Vt[64][72], const bf16x8 qf[2],
                                          f32x4 o_acc[4], float& m_i, float& l_i,
                                          int kt, int qt_tile, int w, int lr,
                                          int lq, int lq4, int base16, int qrow_l) {
  f32x4 sa[4] = {};
#pragma unroll
  for (int mb = 0; mb < 4; ++mb)
#pragma unroll
    for (int kk = 0; kk < 2; ++kk) {
      bf16x8 kf = *(const bf16x8*)&Ks[mb * 16 + lr][kk * 32 + lq * 8];
      sa[mb] = __builtin_amdgcn_mfma_f32_16x16x32_bf16(kf, qf[kk], sa[mb], 0, 0, 0);
    }
  float sc[4][4];
  float m_new = m_i;
#pragma unroll
  for (int mb = 0; mb < 4; ++mb)
#pragma unroll
    for (int i = 0; i < 4; ++i) {
      float sv = sa[mb][i] * 0.125f;
      if (kt == qt_tile && (mb * 16 + lq4 + i) > qrow_l) sv = -3.0e4f;
      sc[mb][i] = sv;
      m_new = fmaxf(m_new, sv);
    }
  m_new = fmaxf(m_new, __shfl_xor(m_new, 16));
  m_new = fmaxf(m_new, __shfl_xor(m_new, 32));
  float alpha = __expf(m_i - m_new);
  m_i = m_new;
  float p[4][4], sm = 0.f;
#pragma unroll
  for (int mb = 0; mb < 4; ++mb)
#pragma unroll
    for (int i = 0; i < 4; ++i) { p[mb][i] = __expf(sc[mb][i] - m_new); sm += p[mb][i]; }
  sm += __shfl_xor(sm, 16);
  sm += __shfl_xor(sm, 32);
  l_i = l_i * alpha + sm;
#pragma unroll
  for (int mb = 0; mb < 4; ++mb) {
    uint2 pk;
    pk.x = (uint32_t)f2b(p[mb][0]) | ((uint32_t)f2b(p[mb][1]) << 16);
    pk.y = (uint32_t)f2b(p[mb][2]) | ((uint32_t)f2b(p[mb][3]) << 16);
    *(uint2*)&QP[w * 16 + lr][mb * 16 + lq4] = pk;
  }
#pragma unroll
  for (int i = 0; i < 4; ++i) {
    float ai = __shfl(alpha, base16 | (lq4 + i));
    o_acc[0][i] *= ai; o_acc[1][i] *= ai;
    o_acc[2][i] *= ai; o_acc[3][i] *= ai;
  }
  asm volatile("s_waitcnt lgkmcnt(0)" ::: "memory");
#pragma unroll
  for (int kk = 0; kk < 2; ++kk) {
    bf16x8 pf = *(const bf16x8*)&QP[w * 16 + lr][kk * 32 + lq * 8];
#pragma unroll
    for (int nb = 0; nb < 4; ++nb) {
      bf16x8 vf = *(const bf16x8*)&Vt[nb * 16 + lr][kk * 32 + lq * 8];
      o_acc[nb] = __builtin_amdgcn_mfma_f32_16x16x32_bf16(pf, vf, o_acc[nb], 0, 0, 0);
    }
  }
}

// ---------------------------------------------------------------------------
// Kernel 2: causal flash attention — R5-verbatim (K/V dbuf, 1 barrier/kt).
// ---------------------------------------------------------------------------
__global__ __launch_bounds__(256) void k_attn(const u16* __restrict__ Q,
                                              const u16* __restrict__ K,
                                              const u16* __restrict__ V,
                                              u16* __restrict__ AO) {
  __shared__ u16 QP[64][72];
  __shared__ u16 Ks[2][64][72];
  __shared__ u16 Vt[2][64][72];
  const int qtA = 31 - blockIdx.x;      // 16..31
  const int qtB = blockIdx.x;           // 0..15  (qtB < qtA always)
  const int bh = blockIdx.y;
  const int b = bh >> 4, h = bh & 15;
  const u16* Qg = Q + (bh * 2048) * 64;
  const u16* Kg = K + bh * 2048 * 64;
  const u16* Vg = V + (long)bh * 64 * 2048;
  const int t = threadIdx.x, w = t >> 6, lane = t & 63;
  const int lr = lane & 15, lq = lane >> 4;
  const int lq4 = lq * 4;
  const int base16 = lane & 48;
  const int r0 = t >> 3, c0 = (t & 7) * 8;
  const int qrow_l = w * 16 + lr;

  // kt=0 K/V loads issue first: overlap the Q staging below.
  uint4 pk0 = *(const uint4*)&Kg[r0 * 64 + c0];
  uint4 pk1 = *(const uint4*)&Kg[(r0 + 32) * 64 + c0];
  uint4 pv0 = *(const uint4*)&Vg[r0 * 2048 + c0];
  uint4 pv1 = *(const uint4*)&Vg[(r0 + 32) * 2048 + c0];

  bf16x8 qfA[2], qfB[2];
  *(uint4*)&QP[r0][c0]      = *(const uint4*)&Qg[(qtA * 64 + r0) * 64 + c0];
  *(uint4*)&QP[r0 + 32][c0] = *(const uint4*)&Qg[(qtA * 64 + r0 + 32) * 64 + c0];
  __syncthreads();
#pragma unroll
  for (int kk = 0; kk < 2; ++kk)
    qfA[kk] = *(const bf16x8*)&QP[w * 16 + lr][kk * 32 + lq * 8];
  __syncthreads();
  *(uint4*)&QP[r0][c0]      = *(const uint4*)&Qg[(qtB * 64 + r0) * 64 + c0];
  *(uint4*)&QP[r0 + 32][c0] = *(const uint4*)&Qg[(qtB * 64 + r0 + 32) * 64 + c0];
  __syncthreads();
#pragma unroll
  for (int kk = 0; kk < 2; ++kk)
    qfB[kk] = *(const bf16x8*)&QP[w * 16 + lr][kk * 32 + lq * 8];

  // tile 0 -> buf0; tile 1 -> regs (qtA >= 16 so tile 1 always exists)
  *(uint4*)&Ks[0][r0][c0]      = pk0;
  *(uint4*)&Ks[0][r0 + 32][c0] = pk1;
  *(uint4*)&Vt[0][r0][c0]      = pv0;
  *(uint4*)&Vt[0][r0 + 32][c0] = pv1;
  pk0 = *(const uint4*)&Kg[(64 + r0) * 64 + c0];
  pk1 = *(const uint4*)&Kg[(64 + r0 + 32) * 64 + c0];
  pv0 = *(const uint4*)&Vg[r0 * 2048 + 64 + c0];
  pv1 = *(const uint4*)&Vg[(r0 + 32) * 2048 + 64 + c0];
  __syncthreads();                      // buf0 visible everywhere

  float m_iA = -3.0e4f, l_iA = 0.f, m_iB = -3.0e4f, l_iB = 0.f;
  f32x4 o_accA[4] = {}, o_accB[4] = {};

  int cur = 0;
  for (int kt = 0; kt <= qtA; ++kt) {
    if (kt + 1 <= qtA) {                // write tile kt+1 -> other buffer
      *(uint4*)&Ks[cur ^ 1][r0][c0]      = pk0;
      *(uint4*)&Ks[cur ^ 1][r0 + 32][c0] = pk1;
      *(uint4*)&Vt[cur ^ 1][r0][c0]      = pv0;
      *(uint4*)&Vt[cur ^ 1][r0 + 32][c0] = pv1;
    }
    if (kt + 2 <= qtA) {                // prefetch tile kt+2
      const int kn = kt + 2;
      pk0 = *(const uint4*)&Kg[(kn * 64 + r0) * 64 + c0];
      pk1 = *(const uint4*)&Kg[(kn * 64 + r0 + 32) * 64 + c0];
      pv0 = *(const uint4*)&Vg[r0 * 2048 + kn * 64 + c0];
      pv1 = *(const uint4*)&Vg[(r0 + 32) * 2048 + kn * 64 + c0];
    }

    attn_tile(QP, Ks[cur], Vt[cur], qfA, o_accA, m_iA, l_iA, kt, qtA,
              w, lr, lq, lq4, base16, qrow_l);
    if (kt <= qtB) {
      asm volatile("s_waitcnt lgkmcnt(0)" ::: "memory");
      attn_tile(QP, Ks[cur], Vt[cur], qfB, o_accB, m_iB, l_iB, kt, qtB,
                w, lr, lq, lq4, base16, qrow_l);
    }
    __syncthreads();                    // ONE barrier per kt
    cur ^= 1;
  }
  float linvA = 1.0f / l_iA, linvB = 1.0f / l_iB;
#pragma unroll
  for (int i = 0; i < 4; ++i) {
    float invA = __shfl(linvA, base16 | (lq4 + i));
    float invB = __shfl(linvB, base16 | (lq4 + i));
    int rowA = qtA * 64 + w * 16 + lq4 + i;
    int rowB = qtB * 64 + w * 16 + lq4 + i;
    int obA = (b * 2048 + rowA) * 1024 + h * 64;
    int obB = (b * 2048 + rowB) * 1024 + h * 64;
#pragma unroll
    for (int nb = 0; nb < 4; ++nb) {
      AO[obA + nb * 16 + lr] = f2b(o_accA[nb][i] * invA);
      AO[obB + nb * 16 + lr] = f2b(o_accB[nb][i] * invB);
    }
  }
}

// ---------------------------------------------------------------------------
// Kernel 3: out = ao @ w_out^T — R5-verbatim (gload_lds dbuf, XOR granule
// swizzle both sides, 64m x 128n, 512 blocks; inline probe).
// ---------------------------------------------------------------------------
__global__ __launch_bounds__(256) void k_gemm_out(const u16* __restrict__ A,
                                                  const void* __restrict__ Bv,
                                                  void* __restrict__ Cv) {
  __shared__ u16 As[2][64][32];       // [buf]
  __shared__ u16 Bs[2][2][64][32];    // [buf][n-half]
  __shared__ int cnt_sh;
  const int t = threadIdx.x, w = t >> 6, lane = t & 63;
  const int mode = probe_mode((const u16*)Bv, t, &cnt_sh);
  const int n0 = blockIdx.x * 128, m0 = blockIdx.y * 64;
  const int lr = lane & 15, lq = lane >> 4;
  f32x4 acc[2][4] = {};               // [n-e][mt]
  const int rA = t >> 2;
  const int gcol = (((t & 3) ^ ((rA >> 1) & 3)) << 3);
  const int aoff  = (m0 + rA) * 1024 + gcol;
  const int boff0 = (n0 + rA) * 1024 + gcol;
  const int boff1 = boff0 + 65536;    // +64 rows of w_out

  if (mode == 0) {
    const u16* Bp = (const u16*)Bv;
#define STAGE_OUT(buf, kk)                                                     \
    do {                                                                       \
      GLOAD16(A + aoff + (kk),   &As[buf][(w << 4)][0]);                       \
      GLOAD16(Bp + boff0 + (kk), &Bs[buf][0][(w << 4)][0]);                    \
      GLOAD16(Bp + boff1 + (kk), &Bs[buf][1][(w << 4)][0]);                    \
    } while (0)
    STAGE_OUT(0, 0);
    asm volatile("s_waitcnt vmcnt(0)" ::: "memory");
    __syncthreads();
    int cur = 0;
    for (int k0 = 0; k0 < 1024; k0 += 32) {
      if (k0 + 32 < 1024) STAGE_OUT(cur ^ 1, k0 + 32);
      bf16x8 bfx[2];
      const int rowB = (w << 4) + lr;
      const int scB = ((lq ^ ((rowB >> 1) & 3)) << 3);
#pragma unroll
      for (int e = 0; e < 2; ++e)
        bfx[e] = *(const bf16x8*)&Bs[cur][e][rowB][scB];
#pragma unroll
      for (int mt = 0; mt < 4; ++mt) {
        const int row = (mt << 4) + lr;
        const int sc = ((lq ^ ((row >> 1) & 3)) << 3);
        bf16x8 af = *(const bf16x8*)&As[cur][row][sc];
#pragma unroll
        for (int e = 0; e < 2; ++e)
          acc[e][mt] = __builtin_amdgcn_mfma_f32_16x16x32_bf16(af, bfx[e], acc[e][mt], 0, 0, 0);
      }
      __syncthreads();
      cur ^= 1;
    }
#undef STAGE_OUT
  } else {
    // fp32-W fallback (dead in practice): A is always bf16 (our ao buffer)
    const float* Bf = (const float*)Bv;
    for (int k0 = 0; k0 < 1024; k0 += 32) {
      __syncthreads();
      *(uint4*)&As[0][rA][(t & 3) << 3] = *(const uint4*)(A + (m0 + rA) * 1024 + ((t & 3) << 3) + k0);
#pragma unroll
      for (int ee = 0; ee < 8; ++ee) {
        const int pc = ((t & 3) << 3) + ee;
        Bs[0][0][rA][pc] = f2b(Bf[(n0 + rA) * 1024 + pc + k0]);
        Bs[0][1][rA][pc] = f2b(Bf[(n0 + rA) * 1024 + 65536 + pc + k0]);
      }
      __syncthreads();
      bf16x8 bfx[2];
      const int rowB = (w << 4) + lr;
#pragma unroll
      for (int e = 0; e < 2; ++e)
        bfx[e] = *(const bf16x8*)&Bs[0][e][rowB][lq * 8];
#pragma unroll
      for (int mt = 0; mt < 4; ++mt) {
        bf16x8 af = *(const bf16x8*)&As[0][(mt << 4) + lr][lq * 8];
#pragma unroll
        for (int e = 0; e < 2; ++e)
          acc[e][mt] = __builtin_amdgcn_mfma_f32_16x16x32_bf16(af, bfx[e], acc[e][mt], 0, 0, 0);
      }
    }
  }
#pragma unroll
  for (int e = 0; e < 2; ++e) {
    const int col = n0 + e * 64 + (w << 4) + lr;
    if (mode == 0) {
      u16* C = (u16*)Cv;
#pragma unroll
      for (int mt = 0; mt < 4; ++mt)
#pragma unroll
        for (int i = 0; i < 4; ++i)
          C[(m0 + mt * 16 + lq * 4 + i) * 1024 + col] = f2b(acc[e][mt][i]);
    } else {
      float* C = (float*)Cv;
#pragma unroll
      for (int mt = 0; mt < 4; ++mt)
#pragma unroll
        for (int i = 0; i < 4; ++i)
          C[(m0 + mt * 16 + lq * 4 + i) * 1024 + col] = acc[e][mt][i];
    }
  }
}

// ---------------------------------------------------------------------------
extern "C" void kernel_launch(void* const* d_in, const int* in_sizes, int n_in,
                              void* d_out, int out_size, void* d_ws, size_t ws_size,
                              hipStream_t stream) {
  const void* x    = d_in[0];   // (4096,1024)
  const void* wqkv = d_in[1];   // (3072,1024)
  const void* wout = d_in[2];   // (1024,1024)

  // ws layout: [reserved 256B][q 8.39MB][k 8.39MB][v^T 8.39MB][ao]
  u16* qb = (u16*)((char*)d_ws + 256);
  u16* kb = qb + 4194304;
  u16* vb = kb + 4194304;
  u16* ao = vb + 4194304;

  k_qkv_rope<<<dim3(24, 32), 256, 0, stream>>>(x, wqkv, qb, kb, vb);
  k_attn    <<<dim3(16, 32), 256, 0, stream>>>(qb, kb, vb, ao);
  k_gemm_out<<<dim3(8, 64), 256, 0, stream>>>(ao, wout, d_out);
}

// Round 7
// 300.669 us; speedup vs baseline: 1.0899x; 1.0899x over previous
//
#include <hip/hip_runtime.h>
#include <stdint.h>

typedef uint16_t u16;
typedef __attribute__((ext_vector_type(8))) short bf16x8;
typedef __attribute__((ext_vector_type(4))) float f32x4;

__device__ inline u16 f2b(float f) {          // fp32 -> bf16 RNE
  uint32_t u = __float_as_uint(f);
  u += 0x7FFF + ((u >> 16) & 1);
  return (u16)(u >> 16);
}
__device__ inline float b2f(u16 h) {          // bf16 -> fp32 exact
  return __uint_as_float(((uint32_t)h) << 16);
}

// Async global->LDS DMA, 16B per lane (used by k_gemm_out only).
typedef __attribute__((address_space(1))) void gvoid;
typedef __attribute__((address_space(3))) void lvoid;
#define GLOAD16(gp, lp)                                                        \
  __builtin_amdgcn_global_load_lds((gvoid*)(gp), (lvoid*)(lp), 16, 0, 0)

// ---------------------------------------------------------------------------
// Inline dtype probe: mode 0 = bf16, 1 = fp32 (R4-proven).
// ---------------------------------------------------------------------------
__device__ __forceinline__ int probe_mode(const u16* __restrict__ P, int t,
                                          int* cnt_sh) {
  if (t == 0) *cnt_sh = 0;
  __syncthreads();
  float av = fabsf(b2f(P[t * 2]));
  if (av >= 1000.0f) atomicAdd(cnt_sh, 1);
  __syncthreads();
  return (*cnt_sh > 16) ? 1 : 0;
}

// ---------------------------------------------------------------------------
// Kernel 1: qkv = x @ w_qkv^T — R5-VERBATIM (proven 70 us local optimum;
// R1/R2/R3/R6 structural variants all regressed). LDS double-buffer,
// single barrier per K-step, register prefetch.
// ---------------------------------------------------------------------------
__global__ __launch_bounds__(256) void k_qkv_rope(const void* __restrict__ Xv,
                                                  const void* __restrict__ Wv,
                                                  u16* __restrict__ Qo,
                                                  u16* __restrict__ Ko,
                                                  u16* __restrict__ Vo) {
  __shared__ u16 As[2][2][64][40];        // [buf][m-half]
  __shared__ u16 Bs[2][3][64][40];        // [buf][e]
  __shared__ float Cs[64][66];
  __shared__ int cnt_sh;
  const int t = threadIdx.x, w = t >> 6, lane = t & 63;
  const int mode = probe_mode((const u16*)Xv, t, &cnt_sh);
  const int h = blockIdx.x;               // head 0..15
  const int n0h = h * 64;
  const int m0 = blockIdx.y * 128;        // two 64-row m-tiles
  const int lr = lane & 15, lq = lane >> 4;
  f32x4 acc[3][2][4] = {};                // [e][m-half][mt]
  const int rA = t >> 2, cA = (t & 3) * 8;
  const int aoff0 = (m0 + rA) * 1024 + cA;
  const int aoff1 = (m0 + 64 + rA) * 1024 + cA;
  const int boff0 = (n0h + rA) * 1024 + cA;

  if (mode == 0) {
    const u16* Xp = (const u16*)Xv;
    const u16* Wp = (const u16*)Wv;
    // tile 0 -> regs -> buf0
    uint4 pa0 = *(const uint4*)(Xp + aoff0);
    uint4 pa1 = *(const uint4*)(Xp + aoff1);
    uint4 pb0 = *(const uint4*)(Wp + boff0);
    uint4 pb1 = *(const uint4*)(Wp + boff0 + 1048576);
    uint4 pb2 = *(const uint4*)(Wp + boff0 + 2097152);
    *(uint4*)&As[0][0][rA][cA] = pa0;
    *(uint4*)&As[0][1][rA][cA] = pa1;
    *(uint4*)&Bs[0][0][rA][cA] = pb0;
    *(uint4*)&Bs[0][1][rA][cA] = pb1;
    *(uint4*)&Bs[0][2][rA][cA] = pb2;
    // tile 1 -> regs
    pa0 = *(const uint4*)(Xp + aoff0 + 32);
    pa1 = *(const uint4*)(Xp + aoff1 + 32);
    pb0 = *(const uint4*)(Wp + boff0 + 32);
    pb1 = *(const uint4*)(Wp + boff0 + 1048576 + 32);
    pb2 = *(const uint4*)(Wp + boff0 + 2097152 + 32);
    __syncthreads();                      // buf0 visible, tile-1 regs resident
    int cur = 0;
    for (int k0 = 0; k0 < 1024; k0 += 32) {
      if (k0 + 32 < 1024) {               // write tile k+1 -> other buffer
        *(uint4*)&As[cur ^ 1][0][rA][cA] = pa0;
        *(uint4*)&As[cur ^ 1][1][rA][cA] = pa1;
        *(uint4*)&Bs[cur ^ 1][0][rA][cA] = pb0;
        *(uint4*)&Bs[cur ^ 1][1][rA][cA] = pb1;
        *(uint4*)&Bs[cur ^ 1][2][rA][cA] = pb2;
      }
      if (k0 + 64 < 1024) {               // prefetch tile k+2
        const int kn = k0 + 64;
        pa0 = *(const uint4*)(Xp + aoff0 + kn);
        pa1 = *(const uint4*)(Xp + aoff1 + kn);
        pb0 = *(const uint4*)(Wp + boff0 + kn);
        pb1 = *(const uint4*)(Wp + boff0 + 1048576 + kn);
        pb2 = *(const uint4*)(Wp + boff0 + 2097152 + kn);
      }
      bf16x8 bf[3];                       // compute from buf[cur]
#pragma unroll
      for (int e = 0; e < 3; ++e)
        bf[e] = *(const bf16x8*)&Bs[cur][e][(w << 4) + lr][lq * 8];
#pragma unroll
      for (int mt = 0; mt < 4; ++mt) {
        bf16x8 af0 = *(const bf16x8*)&As[cur][0][(mt << 4) + lr][lq * 8];
        bf16x8 af1 = *(const bf16x8*)&As[cur][1][(mt << 4) + lr][lq * 8];
#pragma unroll
        for (int e = 0; e < 3; ++e) {
          acc[e][0][mt] = __builtin_amdgcn_mfma_f32_16x16x32_bf16(af0, bf[e], acc[e][0][mt], 0, 0, 0);
          acc[e][1][mt] = __builtin_amdgcn_mfma_f32_16x16x32_bf16(af1, bf[e], acc[e][1][mt], 0, 0, 0);
        }
      }
      __syncthreads();                    // ONE barrier per step
      cur ^= 1;
    }
  } else {
    // fp32 fallback (dead in practice): single-buffer, 2-barrier
    for (int k0 = 0; k0 < 1024; k0 += 32) {
      __syncthreads();
      const float* Xf = (const float*)Xv;
      const float* Wf = (const float*)Wv;
#pragma unroll
      for (int ee = 0; ee < 8; ++ee) {
        As[0][0][rA][cA + ee] = f2b(Xf[aoff0 + k0 + ee]);
        As[0][1][rA][cA + ee] = f2b(Xf[aoff1 + k0 + ee]);
        Bs[0][0][rA][cA + ee] = f2b(Wf[boff0 + k0 + ee]);
        Bs[0][1][rA][cA + ee] = f2b(Wf[boff0 + 1048576 + k0 + ee]);
        Bs[0][2][rA][cA + ee] = f2b(Wf[boff0 + 2097152 + k0 + ee]);
      }
      __syncthreads();
      bf16x8 bf[3];
#pragma unroll
      for (int e = 0; e < 3; ++e)
        bf[e] = *(const bf16x8*)&Bs[0][e][(w << 4) + lr][lq * 8];
#pragma unroll
      for (int mt = 0; mt < 4; ++mt) {
        bf16x8 af0 = *(const bf16x8*)&As[0][0][(mt << 4) + lr][lq * 8];
        bf16x8 af1 = *(const bf16x8*)&As[0][1][(mt << 4) + lr][lq * 8];
#pragma unroll
        for (int e = 0; e < 3; ++e) {
          acc[e][0][mt] = __builtin_amdgcn_mfma_f32_16x16x32_bf16(af0, bf[e], acc[e][0][mt], 0, 0, 0);
          acc[e][1][mt] = __builtin_amdgcn_mfma_f32_16x16x32_bf16(af1, bf[e], acc[e][1][mt], 0, 0, 0);
        }
      }
    }
  }

  // epilogue: 6x Cs round-trip (R12-verbatim)
  for (int f = 0; f < 2; ++f) {
    const int m0f = m0 + f * 64;
    for (int e = 0; e < 3; ++e) {
      __syncthreads();
      {
        const int col = (w << 4) + lr;
#pragma unroll
        for (int mt = 0; mt < 4; ++mt)
#pragma unroll
          for (int i = 0; i < 4; ++i)
            Cs[mt * 16 + lq * 4 + i][col] = acc[e][f][mt][i];
      }
      __syncthreads();
      if (e == 2) {
        const int sx = t & 63, dh0 = (t >> 6) * 16;
        const int m = m0f + sx, b = m >> 11, s = m & 2047;
        const long hb = (long)(b * 16 + h) * 64;
#pragma unroll
        for (int u = 0; u < 16; ++u) {
          int dh = dh0 + u;
          Vo[(hb + dh) * 2048 + s] = f2b(Cs[sx][dh]);
        }
      } else {
        const int r = t >> 2, dh0 = (t & 3) * 16;
        const int m = m0f + r, b = m >> 11, s = m & 2047;
        const int obase = ((b * 16 + h) * 2048 + s) * 64;
        u16* O = (e == 0) ? Qo : Ko;
#pragma unroll
        for (int u = 0; u < 16; ++u) {
          int dh = dh0 + u;
          float v  = Cs[r][dh];
          float vp = Cs[r][dh ^ 32];
          float sign = (dh < 32) ? -1.0f : 1.0f;
          float fr  = __expf((float)(dh & 31) * -0.28782314f);
          float ang = (float)s * fr;
          float sn = __sinf(ang), cs = __cosf(ang);
          O[obase + dh] = f2b(v * cs + sign * vp * sn);
        }
      }
    }
  }
}

// ---------------------------------------------------------------------------
// Attention tile phases (R9-proven math, split so MFMA/VALU can interleave).
// ---------------------------------------------------------------------------
__device__ __forceinline__ void qk_tile(const u16 Ks[64][72], const bf16x8 qf[2],
                                        f32x4 sa[4], int lr, int lq) {
#pragma unroll
  for (int mb = 0; mb < 4; ++mb) {
    sa[mb] = (f32x4){0.f, 0.f, 0.f, 0.f};
#pragma unroll
    for (int kk = 0; kk < 2; ++kk) {
      bf16x8 kf = *(const bf16x8*)&Ks[mb * 16 + lr][kk * 32 + lq * 8];
      sa[mb] = __builtin_amdgcn_mfma_f32_16x16x32_bf16(kf, qf[kk], sa[mb], 0, 0, 0);
    }
  }
}

__device__ __forceinline__ void softmax_tile(const f32x4 sa[4], u16 P[64][72],
                                             f32x4 o_acc[4], float& m_i, float& l_i,
                                             int kt, int qt_tile, int w, int lr,
                                             int lq4, int base16, int qrow_l) {
  float sc[4][4];
  float m_new = m_i;
#pragma unroll
  for (int mb = 0; mb < 4; ++mb)
#pragma unroll
    for (int i = 0; i < 4; ++i) {
      float sv = sa[mb][i] * 0.125f;
      if (kt == qt_tile && (mb * 16 + lq4 + i) > qrow_l) sv = -3.0e4f;
      sc[mb][i] = sv;
      m_new = fmaxf(m_new, sv);
    }
  m_new = fmaxf(m_new, __shfl_xor(m_new, 16));
  m_new = fmaxf(m_new, __shfl_xor(m_new, 32));
  float alpha = __expf(m_i - m_new);
  m_i = m_new;
  float p[4][4], sm = 0.f;
#pragma unroll
  for (int mb = 0; mb < 4; ++mb)
#pragma unroll
    for (int i = 0; i < 4; ++i) { p[mb][i] = __expf(sc[mb][i] - m_new); sm += p[mb][i]; }
  sm += __shfl_xor(sm, 16);
  sm += __shfl_xor(sm, 32);
  l_i = l_i * alpha + sm;
#pragma unroll
  for (int mb = 0; mb < 4; ++mb) {
    uint2 pk;
    pk.x = (uint32_t)f2b(p[mb][0]) | ((uint32_t)f2b(p[mb][1]) << 16);
    pk.y = (uint32_t)f2b(p[mb][2]) | ((uint32_t)f2b(p[mb][3]) << 16);
    *(uint2*)&P[w * 16 + lr][mb * 16 + lq4] = pk;
  }
#pragma unroll
  for (int i = 0; i < 4; ++i) {
    float ai = __shfl(alpha, base16 | (lq4 + i));
    o_acc[0][i] *= ai; o_acc[1][i] *= ai;
    o_acc[2][i] *= ai; o_acc[3][i] *= ai;
  }
}

__device__ __forceinline__ void pv_tile(const u16 P[64][72], const u16 Vt[64][72],
                                        f32x4 o_acc[4], int w, int lr, int lq) {
  asm volatile("s_waitcnt lgkmcnt(0)" ::: "memory");
#pragma unroll
  for (int kk = 0; kk < 2; ++kk) {
    bf16x8 pf = *(const bf16x8*)&P[w * 16 + lr][kk * 32 + lq * 8];
#pragma unroll
    for (int nb = 0; nb < 4; ++nb) {
      bf16x8 vf = *(const bf16x8*)&Vt[nb * 16 + lr][kk * 32 + lq * 8];
      o_acc[nb] = __builtin_amdgcn_mfma_f32_16x16x32_bf16(pf, vf, o_acc[nb], 0, 0, 0);
    }
  }
}

// ---------------------------------------------------------------------------
// Kernel 2: causal flash attention, paired q-tiles. THIS ROUND:
// (a) single-buffer K/V + reg-prefetch (R4-proven, == R5 dbuf within 1us)
//     freeing LDS for a second P buffer -> 36.9 KB -> 4 blocks/CU;
// (b) phase interleave: QK_A, softmax_A, QK_B, PV_A, softmax_B, PV_B —
//     softmax_B's VALU chain hides under PV_A's MFMAs (separate pipes,
//     m114); sa reused between tiles so VGPR stays <= 128 for 4 blocks/CU.
// ---------------------------------------------------------------------------
__global__ __launch_bounds__(256, 4) void k_attn(const u16* __restrict__ Q,
                                                 const u16* __restrict__ K,
                                                 const u16* __restrict__ V,
                                                 u16* __restrict__ AO) {
  __shared__ u16 QP[64][72];            // Q staging, then P of tile A
  __shared__ u16 PB[64][72];            // P of tile B
  __shared__ u16 Ks[64][72];
  __shared__ u16 Vt[64][72];
  const int qtA = 31 - blockIdx.x;      // 16..31
  const int qtB = blockIdx.x;           // 0..15  (qtB < qtA always)
  const int bh = blockIdx.y;
  const int b = bh >> 4, h = bh & 15;
  const u16* Qg = Q + (bh * 2048) * 64;
  const u16* Kg = K + bh * 2048 * 64;
  const u16* Vg = V + (long)bh * 64 * 2048;
  const int t = threadIdx.x, w = t >> 6, lane = t & 63;
  const int lr = lane & 15, lq = lane >> 4;
  const int lq4 = lq * 4;
  const int base16 = lane & 48;
  const int r0 = t >> 3, c0 = (t & 7) * 8;
  const int qrow_l = w * 16 + lr;

  // kt=0 K/V loads issue first: overlap the Q staging below.
  uint4 pk0 = *(const uint4*)&Kg[r0 * 64 + c0];
  uint4 pk1 = *(const uint4*)&Kg[(r0 + 32) * 64 + c0];
  uint4 pv0 = *(const uint4*)&Vg[r0 * 2048 + c0];
  uint4 pv1 = *(const uint4*)&Vg[(r0 + 32) * 2048 + c0];

  bf16x8 qfA[2], qfB[2];
  *(uint4*)&QP[r0][c0]      = *(const uint4*)&Qg[(qtA * 64 + r0) * 64 + c0];
  *(uint4*)&QP[r0 + 32][c0] = *(const uint4*)&Qg[(qtA * 64 + r0 + 32) * 64 + c0];
  __syncthreads();
#pragma unroll
  for (int kk = 0; kk < 2; ++kk)
    qfA[kk] = *(const bf16x8*)&QP[w * 16 + lr][kk * 32 + lq * 8];
  __syncthreads();
  *(uint4*)&QP[r0][c0]      = *(const uint4*)&Qg[(qtB * 64 + r0) * 64 + c0];
  *(uint4*)&QP[r0 + 32][c0] = *(const uint4*)&Qg[(qtB * 64 + r0 + 32) * 64 + c0];
  __syncthreads();
#pragma unroll
  for (int kk = 0; kk < 2; ++kk)
    qfB[kk] = *(const bf16x8*)&QP[w * 16 + lr][kk * 32 + lq * 8];

  float m_iA = -3.0e4f, l_iA = 0.f, m_iB = -3.0e4f, l_iB = 0.f;
  f32x4 o_accA[4] = {}, o_accB[4] = {};

  for (int kt = 0; kt <= qtA; ++kt) {
    __syncthreads();                    // prior tile's frag reads done
    *(uint4*)&Ks[r0][c0]      = pk0;
    *(uint4*)&Ks[r0 + 32][c0] = pk1;
    *(uint4*)&Vt[r0][c0]      = pv0;
    *(uint4*)&Vt[r0 + 32][c0] = pv1;
    __syncthreads();                    // writes visible
    if (kt < qtA) {                     // prefetch kt+1 (overlaps compute)
      const int kn = kt + 1;
      pk0 = *(const uint4*)&Kg[(kn * 64 + r0) * 64 + c0];
      pk1 = *(const uint4*)&Kg[(kn * 64 + r0 + 32) * 64 + c0];
      pv0 = *(const uint4*)&Vg[r0 * 2048 + kn * 64 + c0];
      pv1 = *(const uint4*)&Vg[(r0 + 32) * 2048 + kn * 64 + c0];
    }

    const bool doB = (kt <= qtB);
    f32x4 sa[4];                        // reused by both tiles (VGPR budget)
    qk_tile(Ks, qfA, sa, lr, lq);
    softmax_tile(sa, QP, o_accA, m_iA, l_iA, kt, qtA, w, lr, lq4, base16, qrow_l);
    if (doB) qk_tile(Ks, qfB, sa, lr, lq);   // QK_B MFMAs issue before PV_A
    pv_tile(QP, Vt, o_accA, w, lr, lq);      // PV_A MFMAs ...
    if (doB) {
      softmax_tile(sa, PB, o_accB, m_iB, l_iB, kt, qtB, w, lr, lq4, base16, qrow_l);
      pv_tile(PB, Vt, o_accB, w, lr, lq);    // ... hide softmax_B's VALU
    }
  }
  float linvA = 1.0f / l_iA, linvB = 1.0f / l_iB;
#pragma unroll
  for (int i = 0; i < 4; ++i) {
    float invA = __shfl(linvA, base16 | (lq4 + i));
    float invB = __shfl(linvB, base16 | (lq4 + i));
    int rowA = qtA * 64 + w * 16 + lq4 + i;
    int rowB = qtB * 64 + w * 16 + lq4 + i;
    int obA = (b * 2048 + rowA) * 1024 + h * 64;
    int obB = (b * 2048 + rowB) * 1024 + h * 64;
#pragma unroll
    for (int nb = 0; nb < 4; ++nb) {
      AO[obA + nb * 16 + lr] = f2b(o_accA[nb][i] * invA);
      AO[obB + nb * 16 + lr] = f2b(o_accB[nb][i] * invB);
    }
  }
}

// ---------------------------------------------------------------------------
// Kernel 3: out = ao @ w_out^T — R5-verbatim (gload_lds dbuf, XOR granule
// swizzle both sides, 64m x 128n, 512 blocks; inline probe).
// ---------------------------------------------------------------------------
__global__ __launch_bounds__(256) void k_gemm_out(const u16* __restrict__ A,
                                                  const void* __restrict__ Bv,
                                                  void* __restrict__ Cv) {
  __shared__ u16 As[2][64][32];       // [buf]
  __shared__ u16 Bs[2][2][64][32];    // [buf][n-half]
  __shared__ int cnt_sh;
  const int t = threadIdx.x, w = t >> 6, lane = t & 63;
  const int mode = probe_mode((const u16*)Bv, t, &cnt_sh);
  const int n0 = blockIdx.x * 128, m0 = blockIdx.y * 64;
  const int lr = lane & 15, lq = lane >> 4;
  f32x4 acc[2][4] = {};               // [n-e][mt]
  const int rA = t >> 2;
  const int gcol = (((t & 3) ^ ((rA >> 1) & 3)) << 3);
  const int aoff  = (m0 + rA) * 1024 + gcol;
  const int boff0 = (n0 + rA) * 1024 + gcol;
  const int boff1 = boff0 + 65536;    // +64 rows of w_out

  if (mode == 0) {
    const u16* Bp = (const u16*)Bv;
#define STAGE_OUT(buf, kk)                                                     \
    do {                                                                       \
      GLOAD16(A + aoff + (kk),   &As[buf][(w << 4)][0]);                       \
      GLOAD16(Bp + boff0 + (kk), &Bs[buf][0][(w << 4)][0]);                    \
      GLOAD16(Bp + boff1 + (kk), &Bs[buf][1][(w << 4)][0]);                    \
    } while (0)
    STAGE_OUT(0, 0);
    asm volatile("s_waitcnt vmcnt(0)" ::: "memory");
    __syncthreads();
    int cur = 0;
    for (int k0 = 0; k0 < 1024; k0 += 32) {
      if (k0 + 32 < 1024) STAGE_OUT(cur ^ 1, k0 + 32);
      bf16x8 bfx[2];
      const int rowB = (w << 4) + lr;
      const int scB = ((lq ^ ((rowB >> 1) & 3)) << 3);
#pragma unroll
      for (int e = 0; e < 2; ++e)
        bfx[e] = *(const bf16x8*)&Bs[cur][e][rowB][scB];
#pragma unroll
      for (int mt = 0; mt < 4; ++mt) {
        const int row = (mt << 4) + lr;
        const int sc = ((lq ^ ((row >> 1) & 3)) << 3);
        bf16x8 af = *(const bf16x8*)&As[cur][row][sc];
#pragma unroll
        for (int e = 0; e < 2; ++e)
          acc[e][mt] = __builtin_amdgcn_mfma_f32_16x16x32_bf16(af, bfx[e], acc[e][mt], 0, 0, 0);
      }
      __syncthreads();
      cur ^= 1;
    }
#undef STAGE_OUT
  } else {
    // fp32-W fallback (dead in practice): A is always bf16 (our ao buffer)
    const float* Bf = (const float*)Bv;
    for (int k0 = 0; k0 < 1024; k0 += 32) {
      __syncthreads();
      *(uint4*)&As[0][rA][(t & 3) << 3] = *(const uint4*)(A + (m0 + rA) * 1024 + ((t & 3) << 3) + k0);
#pragma unroll
      for (int ee = 0; ee < 8; ++ee) {
        const int pc = ((t & 3) << 3) + ee;
        Bs[0][0][rA][pc] = f2b(Bf[(n0 + rA) * 1024 + pc + k0]);
        Bs[0][1][rA][pc] = f2b(Bf[(n0 + rA) * 1024 + 65536 + pc + k0]);
      }
      __syncthreads();
      bf16x8 bfx[2];
      const int rowB = (w << 4) + lr;
#pragma unroll
      for (int e = 0; e < 2; ++e)
        bfx[e] = *(const bf16x8*)&Bs[0][e][rowB][lq * 8];
#pragma unroll
      for (int mt = 0; mt < 4; ++mt) {
        bf16x8 af = *(const bf16x8*)&As[0][(mt << 4) + lr][lq * 8];
#pragma unroll
        for (int e = 0; e < 2; ++e)
          acc[e][mt] = __builtin_amdgcn_mfma_f32_16x16x32_bf16(af, bfx[e], acc[e][mt], 0, 0, 0);
      }
    }
  }
#pragma unroll
  for (int e = 0; e < 2; ++e) {
    const int col = n0 + e * 64 + (w << 4) + lr;
    if (mode == 0) {
      u16* C = (u16*)Cv;
#pragma unroll
      for (int mt = 0; mt < 4; ++mt)
#pragma unroll
        for (int i = 0; i < 4; ++i)
          C[(m0 + mt * 16 + lq * 4 + i) * 1024 + col] = f2b(acc[e][mt][i]);
    } else {
      float* C = (float*)Cv;
#pragma unroll
      for (int mt = 0; mt < 4; ++mt)
#pragma unroll
        for (int i = 0; i < 4; ++i)
          C[(m0 + mt * 16 + lq * 4 + i) * 1024 + col] = acc[e][mt][i];
    }
  }
}

// ---------------------------------------------------------------------------
extern "C" void kernel_launch(void* const* d_in, const int* in_sizes, int n_in,
                              void* d_out, int out_size, void* d_ws, size_t ws_size,
                              hipStream_t stream) {
  const void* x    = d_in[0];   // (4096,1024)
  const void* wqkv = d_in[1];   // (3072,1024)
  const void* wout = d_in[2];   // (1024,1024)

  // ws layout: [reserved 256B][q 8.39MB][k 8.39MB][v^T 8.39MB][ao]
  u16* qb = (u16*)((char*)d_ws + 256);
  u16* kb = qb + 4194304;
  u16* vb = kb + 4194304;
  u16* ao = vb + 4194304;

  k_qkv_rope<<<dim3(16, 32), 256, 0, stream>>>(x, wqkv, qb, kb, vb);
  k_attn    <<<dim3(16, 32), 256, 0, stream>>>(qb, kb, vb, ao);
  k_gemm_out<<<dim3(8, 64), 256, 0, stream>>>(ao, wout, d_out);
}

// Round 8
// 213.315 us; speedup vs baseline: 1.5362x; 1.4095x over previous
//
#include <hip/hip_runtime.h>
#include <stdint.h>

typedef uint16_t u16;
typedef __attribute__((ext_vector_type(8))) short bf16x8;
typedef __attribute__((ext_vector_type(4))) float f32x4;

__device__ inline u16 f2b(float f) {          // fp32 -> bf16 RNE
  uint32_t u = __float_as_uint(f);
  u += 0x7FFF + ((u >> 16) & 1);
  return (u16)(u >> 16);
}
__device__ inline float b2f(u16 h) {          // bf16 -> fp32 exact
  return __uint_as_float(((uint32_t)h) << 16);
}

// Async global->LDS DMA, 16B per lane (used by k_gemm_out only).
typedef __attribute__((address_space(1))) void gvoid;
typedef __attribute__((address_space(3))) void lvoid;
#define GLOAD16(gp, lp)                                                        \
  __builtin_amdgcn_global_load_lds((gvoid*)(gp), (lvoid*)(lp), 16, 0, 0)

// ---------------------------------------------------------------------------
// Inline dtype probe: mode 0 = bf16, 1 = fp32 (R4-proven).
// ---------------------------------------------------------------------------
__device__ __forceinline__ int probe_mode(const u16* __restrict__ P, int t,
                                          int* cnt_sh) {
  if (t == 0) *cnt_sh = 0;
  __syncthreads();
  float av = fabsf(b2f(P[t * 2]));
  if (av >= 1000.0f) atomicAdd(cnt_sh, 1);
  __syncthreads();
  return (*cnt_sh > 16) ? 1 : 0;
}

// ---------------------------------------------------------------------------
// Kernel 1: qkv = x @ w_qkv^T — R5-VERBATIM loop (proven 70 us optimum).
// THIS ROUND: XCD-aware block remap only (T1). id%8 = XCD; each XCD owns
// m-tiles [4*xcd, 4*xcd+4) (X slice 1MB, L2-resident) iterated inner,
// heads outer -> X fetched once per XCD instead of fully re-fetched by all 8.
// ---------------------------------------------------------------------------
__global__ __launch_bounds__(256) void k_qkv_rope(const void* __restrict__ Xv,
                                                  const void* __restrict__ Wv,
                                                  u16* __restrict__ Qo,
                                                  u16* __restrict__ Ko,
                                                  u16* __restrict__ Vo) {
  __shared__ u16 As[2][2][64][40];        // [buf][m-half]
  __shared__ u16 Bs[2][3][64][40];        // [buf][e]
  __shared__ float Cs[64][66];
  __shared__ int cnt_sh;
  const int t = threadIdx.x, w = t >> 6, lane = t & 63;
  const int mode = probe_mode((const u16*)Xv, t, &cnt_sh);
  // XCD swizzle: id in [0,512), xcd = id&7, p = id>>3; h = p>>2 (outer),
  // m-tile = xcd*4 + (p&3) (inner). Bijective since 512 % 8 == 0.
  const int id = blockIdx.y * 16 + blockIdx.x;
  const int xcd = id & 7, p = id >> 3;
  const int h = p >> 2;                   // head 0..15
  const int n0h = h * 64;
  const int m0 = ((xcd << 2) | (p & 3)) << 7;   // m-tile*128
  const int lr = lane & 15, lq = lane >> 4;
  f32x4 acc[3][2][4] = {};                // [e][m-half][mt]
  const int rA = t >> 2, cA = (t & 3) * 8;
  const int aoff0 = (m0 + rA) * 1024 + cA;
  const int aoff1 = (m0 + 64 + rA) * 1024 + cA;
  const int boff0 = (n0h + rA) * 1024 + cA;

  if (mode == 0) {
    const u16* Xp = (const u16*)Xv;
    const u16* Wp = (const u16*)Wv;
    // tile 0 -> regs -> buf0
    uint4 pa0 = *(const uint4*)(Xp + aoff0);
    uint4 pa1 = *(const uint4*)(Xp + aoff1);
    uint4 pb0 = *(const uint4*)(Wp + boff0);
    uint4 pb1 = *(const uint4*)(Wp + boff0 + 1048576);
    uint4 pb2 = *(const uint4*)(Wp + boff0 + 2097152);
    *(uint4*)&As[0][0][rA][cA] = pa0;
    *(uint4*)&As[0][1][rA][cA] = pa1;
    *(uint4*)&Bs[0][0][rA][cA] = pb0;
    *(uint4*)&Bs[0][1][rA][cA] = pb1;
    *(uint4*)&Bs[0][2][rA][cA] = pb2;
    // tile 1 -> regs
    pa0 = *(const uint4*)(Xp + aoff0 + 32);
    pa1 = *(const uint4*)(Xp + aoff1 + 32);
    pb0 = *(const uint4*)(Wp + boff0 + 32);
    pb1 = *(const uint4*)(Wp + boff0 + 1048576 + 32);
    pb2 = *(const uint4*)(Wp + boff0 + 2097152 + 32);
    __syncthreads();                      // buf0 visible, tile-1 regs resident
    int cur = 0;
    for (int k0 = 0; k0 < 1024; k0 += 32) {
      if (k0 + 32 < 1024) {               // write tile k+1 -> other buffer
        *(uint4*)&As[cur ^ 1][0][rA][cA] = pa0;
        *(uint4*)&As[cur ^ 1][1][rA][cA] = pa1;
        *(uint4*)&Bs[cur ^ 1][0][rA][cA] = pb0;
        *(uint4*)&Bs[cur ^ 1][1][rA][cA] = pb1;
        *(uint4*)&Bs[cur ^ 1][2][rA][cA] = pb2;
      }
      if (k0 + 64 < 1024) {               // prefetch tile k+2
        const int kn = k0 + 64;
        pa0 = *(const uint4*)(Xp + aoff0 + kn);
        pa1 = *(const uint4*)(Xp + aoff1 + kn);
        pb0 = *(const uint4*)(Wp + boff0 + kn);
        pb1 = *(const uint4*)(Wp + boff0 + 1048576 + kn);
        pb2 = *(const uint4*)(Wp + boff0 + 2097152 + kn);
      }
      bf16x8 bf[3];                       // compute from buf[cur]
#pragma unroll
      for (int e = 0; e < 3; ++e)
        bf[e] = *(const bf16x8*)&Bs[cur][e][(w << 4) + lr][lq * 8];
#pragma unroll
      for (int mt = 0; mt < 4; ++mt) {
        bf16x8 af0 = *(const bf16x8*)&As[cur][0][(mt << 4) + lr][lq * 8];
        bf16x8 af1 = *(const bf16x8*)&As[cur][1][(mt << 4) + lr][lq * 8];
#pragma unroll
        for (int e = 0; e < 3; ++e) {
          acc[e][0][mt] = __builtin_amdgcn_mfma_f32_16x16x32_bf16(af0, bf[e], acc[e][0][mt], 0, 0, 0);
          acc[e][1][mt] = __builtin_amdgcn_mfma_f32_16x16x32_bf16(af1, bf[e], acc[e][1][mt], 0, 0, 0);
        }
      }
      __syncthreads();                    // ONE barrier per step
      cur ^= 1;
    }
  } else {
    // fp32 fallback (dead in practice): single-buffer, 2-barrier
    for (int k0 = 0; k0 < 1024; k0 += 32) {
      __syncthreads();
      const float* Xf = (const float*)Xv;
      const float* Wf = (const float*)Wv;
#pragma unroll
      for (int ee = 0; ee < 8; ++ee) {
        As[0][0][rA][cA + ee] = f2b(Xf[aoff0 + k0 + ee]);
        As[0][1][rA][cA + ee] = f2b(Xf[aoff1 + k0 + ee]);
        Bs[0][0][rA][cA + ee] = f2b(Wf[boff0 + k0 + ee]);
        Bs[0][1][rA][cA + ee] = f2b(Wf[boff0 + 1048576 + k0 + ee]);
        Bs[0][2][rA][cA + ee] = f2b(Wf[boff0 + 2097152 + k0 + ee]);
      }
      __syncthreads();
      bf16x8 bf[3];
#pragma unroll
      for (int e = 0; e < 3; ++e)
        bf[e] = *(const bf16x8*)&Bs[0][e][(w << 4) + lr][lq * 8];
#pragma unroll
      for (int mt = 0; mt < 4; ++mt) {
        bf16x8 af0 = *(const bf16x8*)&As[0][0][(mt << 4) + lr][lq * 8];
        bf16x8 af1 = *(const bf16x8*)&As[0][1][(mt << 4) + lr][lq * 8];
#pragma unroll
        for (int e = 0; e < 3; ++e) {
          acc[e][0][mt] = __builtin_amdgcn_mfma_f32_16x16x32_bf16(af0, bf[e], acc[e][0][mt], 0, 0, 0);
          acc[e][1][mt] = __builtin_amdgcn_mfma_f32_16x16x32_bf16(af1, bf[e], acc[e][1][mt], 0, 0, 0);
        }
      }
    }
  }

  // epilogue: 6x Cs round-trip (R12-verbatim)
  for (int f = 0; f < 2; ++f) {
    const int m0f = m0 + f * 64;
    for (int e = 0; e < 3; ++e) {
      __syncthreads();
      {
        const int col = (w << 4) + lr;
#pragma unroll
        for (int mt = 0; mt < 4; ++mt)
#pragma unroll
          for (int i = 0; i < 4; ++i)
            Cs[mt * 16 + lq * 4 + i][col] = acc[e][f][mt][i];
      }
      __syncthreads();
      if (e == 2) {
        const int sx = t & 63, dh0 = (t >> 6) * 16;
        const int m = m0f + sx, b = m >> 11, s = m & 2047;
        const long hb = (long)(b * 16 + h) * 64;
#pragma unroll
        for (int u = 0; u < 16; ++u) {
          int dh = dh0 + u;
          Vo[(hb + dh) * 2048 + s] = f2b(Cs[sx][dh]);
        }
      } else {
        const int r = t >> 2, dh0 = (t & 3) * 16;
        const int m = m0f + r, b = m >> 11, s = m & 2047;
        const int obase = ((b * 16 + h) * 2048 + s) * 64;
        u16* O = (e == 0) ? Qo : Ko;
#pragma unroll
        for (int u = 0; u < 16; ++u) {
          int dh = dh0 + u;
          float v  = Cs[r][dh];
          float vp = Cs[r][dh ^ 32];
          float sign = (dh < 32) ? -1.0f : 1.0f;
          float fr  = __expf((float)(dh & 31) * -0.28782314f);
          float ang = (float)s * fr;
          float sn = __sinf(ang), cs = __cosf(ang);
          O[obase + dh] = f2b(v * cs + sign * vp * sn);
        }
      }
    }
  }
}

// ---------------------------------------------------------------------------
// Per-tile attention body (R9-proven math, factored; per-tile qt/state).
// ---------------------------------------------------------------------------
__device__ __forceinline__ void attn_tile(u16 QP[64][72], u16 Ks[64][72],
                                          u16 Vt[64][72], const bf16x8 qf[2],
                                          f32x4 o_acc[4], float& m_i, float& l_i,
                                          int kt, int qt_tile, int w, int lr,
                                          int lq, int lq4, int base16, int qrow_l) {
  f32x4 sa[4] = {};
#pragma unroll
  for (int mb = 0; mb < 4; ++mb)
#pragma unroll
    for (int kk = 0; kk < 2; ++kk) {
      bf16x8 kf = *(const bf16x8*)&Ks[mb * 16 + lr][kk * 32 + lq * 8];
      sa[mb] = __builtin_amdgcn_mfma_f32_16x16x32_bf16(kf, qf[kk], sa[mb], 0, 0, 0);
    }
  float sc[4][4];
  float m_new = m_i;
#pragma unroll
  for (int mb = 0; mb < 4; ++mb)
#pragma unroll
    for (int i = 0; i < 4; ++i) {
      float sv = sa[mb][i] * 0.125f;
      if (kt == qt_tile && (mb * 16 + lq4 + i) > qrow_l) sv = -3.0e4f;
      sc[mb][i] = sv;
      m_new = fmaxf(m_new, sv);
    }
  m_new = fmaxf(m_new, __shfl_xor(m_new, 16));
  m_new = fmaxf(m_new, __shfl_xor(m_new, 32));
  float alpha = __expf(m_i - m_new);
  m_i = m_new;
  float p[4][4], sm = 0.f;
#pragma unroll
  for (int mb = 0; mb < 4; ++mb)
#pragma unroll
    for (int i = 0; i < 4; ++i) { p[mb][i] = __expf(sc[mb][i] - m_new); sm += p[mb][i]; }
  sm += __shfl_xor(sm, 16);
  sm += __shfl_xor(sm, 32);
  l_i = l_i * alpha + sm;
#pragma unroll
  for (int mb = 0; mb < 4; ++mb) {
    uint2 pk;
    pk.x = (uint32_t)f2b(p[mb][0]) | ((uint32_t)f2b(p[mb][1]) << 16);
    pk.y = (uint32_t)f2b(p[mb][2]) | ((uint32_t)f2b(p[mb][3]) << 16);
    *(uint2*)&QP[w * 16 + lr][mb * 16 + lq4] = pk;
  }
#pragma unroll
  for (int i = 0; i < 4; ++i) {
    float ai = __shfl(alpha, base16 | (lq4 + i));
    o_acc[0][i] *= ai; o_acc[1][i] *= ai;
    o_acc[2][i] *= ai; o_acc[3][i] *= ai;
  }
  asm volatile("s_waitcnt lgkmcnt(0)" ::: "memory");
#pragma unroll
  for (int kk = 0; kk < 2; ++kk) {
    bf16x8 pf = *(const bf16x8*)&QP[w * 16 + lr][kk * 32 + lq * 8];
#pragma unroll
    for (int nb = 0; nb < 4; ++nb) {
      bf16x8 vf = *(const bf16x8*)&Vt[nb * 16 + lr][kk * 32 + lq * 8];
      o_acc[nb] = __builtin_amdgcn_mfma_f32_16x16x32_bf16(pf, vf, o_acc[nb], 0, 0, 0);
    }
  }
}

// ---------------------------------------------------------------------------
// Kernel 2: causal flash attention — R5-verbatim loop (K/V dbuf, 1 barrier
// per kt). THIS ROUND: XCD remap only — each XCD owns 4 bh values (K/V
// working set 2MB, L2-fit) iterated across all 16 q-pairs.
// ---------------------------------------------------------------------------
__global__ __launch_bounds__(256) void k_attn(const u16* __restrict__ Q,
                                              const u16* __restrict__ K,
                                              const u16* __restrict__ V,
                                              u16* __restrict__ AO) {
  __shared__ u16 QP[64][72];
  __shared__ u16 Ks[2][64][72];
  __shared__ u16 Vt[2][64][72];
  // XCD swizzle: bijective (512 % 8 == 0). bh inner (4 per XCD), q-pair outer.
  const int id = blockIdx.y * 16 + blockIdx.x;
  const int xcd = id & 7, p = id >> 3;
  const int bh = (xcd << 2) | (p & 3);  // 4 bh per XCD
  const int qp = p >> 2;                // q-pair 0..15
  const int qtA = 31 - qp;              // 16..31
  const int qtB = qp;                   // 0..15  (qtB < qtA always)
  const int b = bh >> 4, h = bh & 15;
  const u16* Qg = Q + (bh * 2048) * 64;
  const u16* Kg = K + bh * 2048 * 64;
  const u16* Vg = V + (long)bh * 64 * 2048;
  const int t = threadIdx.x, w = t >> 6, lane = t & 63;
  const int lr = lane & 15, lq = lane >> 4;
  const int lq4 = lq * 4;
  const int base16 = lane & 48;
  const int r0 = t >> 3, c0 = (t & 7) * 8;
  const int qrow_l = w * 16 + lr;

  // kt=0 K/V loads issue first: overlap the Q staging below.
  uint4 pk0 = *(const uint4*)&Kg[r0 * 64 + c0];
  uint4 pk1 = *(const uint4*)&Kg[(r0 + 32) * 64 + c0];
  uint4 pv0 = *(const uint4*)&Vg[r0 * 2048 + c0];
  uint4 pv1 = *(const uint4*)&Vg[(r0 + 32) * 2048 + c0];

  bf16x8 qfA[2], qfB[2];
  *(uint4*)&QP[r0][c0]      = *(const uint4*)&Qg[(qtA * 64 + r0) * 64 + c0];
  *(uint4*)&QP[r0 + 32][c0] = *(const uint4*)&Qg[(qtA * 64 + r0 + 32) * 64 + c0];
  __syncthreads();
#pragma unroll
  for (int kk = 0; kk < 2; ++kk)
    qfA[kk] = *(const bf16x8*)&QP[w * 16 + lr][kk * 32 + lq * 8];
  __syncthreads();
  *(uint4*)&QP[r0][c0]      = *(const uint4*)&Qg[(qtB * 64 + r0) * 64 + c0];
  *(uint4*)&QP[r0 + 32][c0] = *(const uint4*)&Qg[(qtB * 64 + r0 + 32) * 64 + c0];
  __syncthreads();
#pragma unroll
  for (int kk = 0; kk < 2; ++kk)
    qfB[kk] = *(const bf16x8*)&QP[w * 16 + lr][kk * 32 + lq * 8];

  // tile 0 -> buf0; tile 1 -> regs (qtA >= 16 so tile 1 always exists)
  *(uint4*)&Ks[0][r0][c0]      = pk0;
  *(uint4*)&Ks[0][r0 + 32][c0] = pk1;
  *(uint4*)&Vt[0][r0][c0]      = pv0;
  *(uint4*)&Vt[0][r0 + 32][c0] = pv1;
  pk0 = *(const uint4*)&Kg[(64 + r0) * 64 + c0];
  pk1 = *(const uint4*)&Kg[(64 + r0 + 32) * 64 + c0];
  pv0 = *(const uint4*)&Vg[r0 * 2048 + 64 + c0];
  pv1 = *(const uint4*)&Vg[(r0 + 32) * 2048 + 64 + c0];
  __syncthreads();                      // buf0 visible everywhere

  float m_iA = -3.0e4f, l_iA = 0.f, m_iB = -3.0e4f, l_iB = 0.f;
  f32x4 o_accA[4] = {}, o_accB[4] = {};

  int cur = 0;
  for (int kt = 0; kt <= qtA; ++kt) {
    if (kt + 1 <= qtA) {                // write tile kt+1 -> other buffer
      *(uint4*)&Ks[cur ^ 1][r0][c0]      = pk0;
      *(uint4*)&Ks[cur ^ 1][r0 + 32][c0] = pk1;
      *(uint4*)&Vt[cur ^ 1][r0][c0]      = pv0;
      *(uint4*)&Vt[cur ^ 1][r0 + 32][c0] = pv1;
    }
    if (kt + 2 <= qtA) {                // prefetch tile kt+2
      const int kn = kt + 2;
      pk0 = *(const uint4*)&Kg[(kn * 64 + r0) * 64 + c0];
      pk1 = *(const uint4*)&Kg[(kn * 64 + r0 + 32) * 64 + c0];
      pv0 = *(const uint4*)&Vg[r0 * 2048 + kn * 64 + c0];
      pv1 = *(const uint4*)&Vg[(r0 + 32) * 2048 + kn * 64 + c0];
    }

    attn_tile(QP, Ks[cur], Vt[cur], qfA, o_accA, m_iA, l_iA, kt, qtA,
              w, lr, lq, lq4, base16, qrow_l);
    if (kt <= qtB) {
      asm volatile("s_waitcnt lgkmcnt(0)" ::: "memory");
      attn_tile(QP, Ks[cur], Vt[cur], qfB, o_accB, m_iB, l_iB, kt, qtB,
                w, lr, lq, lq4, base16, qrow_l);
    }
    __syncthreads();                    // ONE barrier per kt
    cur ^= 1;
  }
  float linvA = 1.0f / l_iA, linvB = 1.0f / l_iB;
#pragma unroll
  for (int i = 0; i < 4; ++i) {
    float invA = __shfl(linvA, base16 | (lq4 + i));
    float invB = __shfl(linvB, base16 | (lq4 + i));
    int rowA = qtA * 64 + w * 16 + lq4 + i;
    int rowB = qtB * 64 + w * 16 + lq4 + i;
    int obA = (b * 2048 + rowA) * 1024 + h * 64;
    int obB = (b * 2048 + rowB) * 1024 + h * 64;
#pragma unroll
    for (int nb = 0; nb < 4; ++nb) {
      AO[obA + nb * 16 + lr] = f2b(o_accA[nb][i] * invA);
      AO[obB + nb * 16 + lr] = f2b(o_accB[nb][i] * invB);
    }
  }
}

// ---------------------------------------------------------------------------
// Kernel 3: out = ao @ w_out^T — R5-verbatim loop (gload_lds dbuf, XOR
// granule swizzle both sides). THIS ROUND: XCD remap only — each XCD owns
// 8 m-tiles (A slice 1MB) iterated inner, n-tiles outer.
// ---------------------------------------------------------------------------
__global__ __launch_bounds__(256) void k_gemm_out(const u16* __restrict__ A,
                                                  const void* __restrict__ Bv,
                                                  void* __restrict__ Cv) {
  __shared__ u16 As[2][64][32];       // [buf]
  __shared__ u16 Bs[2][2][64][32];    // [buf][n-half]
  __shared__ int cnt_sh;
  const int t = threadIdx.x, w = t >> 6, lane = t & 63;
  const int mode = probe_mode((const u16*)Bv, t, &cnt_sh);
  // XCD swizzle: bijective (512 % 8 == 0). m inner (8 per XCD), n outer.
  const int id = blockIdx.y * 8 + blockIdx.x;
  const int xcd = id & 7, p = id >> 3;
  const int n0 = (p >> 3) * 128;
  const int m0 = ((xcd << 3) | (p & 7)) * 64;
  const int lr = lane & 15, lq = lane >> 4;
  f32x4 acc[2][4] = {};               // [n-e][mt]
  const int rA = t >> 2;
  const int gcol = (((t & 3) ^ ((rA >> 1) & 3)) << 3);
  const int aoff  = (m0 + rA) * 1024 + gcol;
  const int boff0 = (n0 + rA) * 1024 + gcol;
  const int boff1 = boff0 + 65536;    // +64 rows of w_out

  if (mode == 0) {
    const u16* Bp = (const u16*)Bv;
#define STAGE_OUT(buf, kk)                                                     \
    do {                                                                       \
      GLOAD16(A + aoff + (kk),   &As[buf][(w << 4)][0]);                       \
      GLOAD16(Bp + boff0 + (kk), &Bs[buf][0][(w << 4)][0]);                    \
      GLOAD16(Bp + boff1 + (kk), &Bs[buf][1][(w << 4)][0]);                    \
    } while (0)
    STAGE_OUT(0, 0);
    asm volatile("s_waitcnt vmcnt(0)" ::: "memory");
    __syncthreads();
    int cur = 0;
    for (int k0 = 0; k0 < 1024; k0 += 32) {
      if (k0 + 32 < 1024) STAGE_OUT(cur ^ 1, k0 + 32);
      bf16x8 bfx[2];
      const int rowB = (w << 4) + lr;
      const int scB = ((lq ^ ((rowB >> 1) & 3)) << 3);
#pragma unroll
      for (int e = 0; e < 2; ++e)
        bfx[e] = *(const bf16x8*)&Bs[cur][e][rowB][scB];
#pragma unroll
      for (int mt = 0; mt < 4; ++mt) {
        const int row = (mt << 4) + lr;
        const int sc = ((lq ^ ((row >> 1) & 3)) << 3);
        bf16x8 af = *(const bf16x8*)&As[cur][row][sc];
#pragma unroll
        for (int e = 0; e < 2; ++e)
          acc[e][mt] = __builtin_amdgcn_mfma_f32_16x16x32_bf16(af, bfx[e], acc[e][mt], 0, 0, 0);
      }
      __syncthreads();
      cur ^= 1;
    }
#undef STAGE_OUT
  } else {
    // fp32-W fallback (dead in practice): A is always bf16 (our ao buffer)
    const float* Bf = (const float*)Bv;
    for (int k0 = 0; k0 < 1024; k0 += 32) {
      __syncthreads();
      *(uint4*)&As[0][rA][(t & 3) << 3] = *(const uint4*)(A + (m0 + rA) * 1024 + ((t & 3) << 3) + k0);
#pragma unroll
      for (int ee = 0; ee < 8; ++ee) {
        const int pc = ((t & 3) << 3) + ee;
        Bs[0][0][rA][pc] = f2b(Bf[(n0 + rA) * 1024 + pc + k0]);
        Bs[0][1][rA][pc] = f2b(Bf[(n0 + rA) * 1024 + 65536 + pc + k0]);
      }
      __syncthreads();
      bf16x8 bfx[2];
      const int rowB = (w << 4) + lr;
#pragma unroll
      for (int e = 0; e < 2; ++e)
        bfx[e] = *(const bf16x8*)&Bs[0][e][rowB][lq * 8];
#pragma unroll
      for (int mt = 0; mt < 4; ++mt) {
        bf16x8 af = *(const bf16x8*)&As[0][(mt << 4) + lr][lq * 8];
#pragma unroll
        for (int e = 0; e < 2; ++e)
          acc[e][mt] = __builtin_amdgcn_mfma_f32_16x16x32_bf16(af, bfx[e], acc[e][mt], 0, 0, 0);
      }
    }
  }
#pragma unroll
  for (int e = 0; e < 2; ++e) {
    const int col = n0 + e * 64 + (w << 4) + lr;
    if (mode == 0) {
      u16* C = (u16*)Cv;
#pragma unroll
      for (int mt = 0; mt < 4; ++mt)
#pragma unroll
        for (int i = 0; i < 4; ++i)
          C[(m0 + mt * 16 + lq * 4 + i) * 1024 + col] = f2b(acc[e][mt][i]);
    } else {
      float* C = (float*)Cv;
#pragma unroll
      for (int mt = 0; mt < 4; ++mt)
#pragma unroll
        for (int i = 0; i < 4; ++i)
          C[(m0 + mt * 16 + lq * 4 + i) * 1024 + col] = acc[e][mt][i];
    }
  }
}

// ---------------------------------------------------------------------------
extern "C" void kernel_launch(void* const* d_in, const int* in_sizes, int n_in,
                              void* d_out, int out_size, void* d_ws, size_t ws_size,
                              hipStream_t stream) {
  const void* x    = d_in[0];   // (4096,1024)
  const void* wqkv = d_in[1];   // (3072,1024)
  const void* wout = d_in[2];   // (1024,1024)

  // ws layout: [reserved 256B][q 8.39MB][k 8.39MB][v^T 8.39MB][ao]
  u16* qb = (u16*)((char*)d_ws + 256);
  u16* kb = qb + 4194304;
  u16* vb = kb + 4194304;
  u16* ao = vb + 4194304;

  k_qkv_rope<<<dim3(16, 32), 256, 0, stream>>>(x, wqkv, qb, kb, vb);
  k_attn    <<<dim3(16, 32), 256, 0, stream>>>(qb, kb, vb, ao);
  k_gemm_out<<<dim3(8, 64), 256, 0, stream>>>(ao, wout, d_out);
}

// Round 9
// 200.837 us; speedup vs baseline: 1.6316x; 1.0621x over previous
//
#include <hip/hip_runtime.h>
#include <stdint.h>

typedef uint16_t u16;
typedef __attribute__((ext_vector_type(8))) short bf16x8;
typedef __attribute__((ext_vector_type(4))) float f32x4;

__device__ inline u16 f2b(float f) {          // fp32 -> bf16 RNE
  uint32_t u = __float_as_uint(f);
  u += 0x7FFF + ((u >> 16) & 1);
  return (u16)(u >> 16);
}
__device__ inline float b2f(u16 h) {          // bf16 -> fp32 exact
  return __uint_as_float(((uint32_t)h) << 16);
}

// Async global->LDS DMA, 16B per lane (used by k_gemm_out only).
typedef __attribute__((address_space(1))) void gvoid;
typedef __attribute__((address_space(3))) void lvoid;
#define GLOAD16(gp, lp)                                                        \
  __builtin_amdgcn_global_load_lds((gvoid*)(gp), (lvoid*)(lp), 16, 0, 0)

// ---------------------------------------------------------------------------
// Inline dtype probe: mode 0 = bf16, 1 = fp32 (R4-proven).
// ---------------------------------------------------------------------------
__device__ __forceinline__ int probe_mode(const u16* __restrict__ P, int t,
                                          int* cnt_sh) {
  if (t == 0) *cnt_sh = 0;
  __syncthreads();
  float av = fabsf(b2f(P[t * 2]));
  if (av >= 1000.0f) atomicAdd(cnt_sh, 1);
  __syncthreads();
  return (*cnt_sh > 16) ? 1 : 0;
}

// ---------------------------------------------------------------------------
// Kernel 1: qkv = x @ w_qkv^T — R8-VERBATIM (R5 loop + T1 XCD remap;
// proven 68 us / FETCH 57 MB).
// ---------------------------------------------------------------------------
__global__ __launch_bounds__(256) void k_qkv_rope(const void* __restrict__ Xv,
                                                  const void* __restrict__ Wv,
                                                  u16* __restrict__ Qo,
                                                  u16* __restrict__ Ko,
                                                  u16* __restrict__ Vo) {
  __shared__ u16 As[2][2][64][40];        // [buf][m-half]
  __shared__ u16 Bs[2][3][64][40];        // [buf][e]
  __shared__ float Cs[64][66];
  __shared__ int cnt_sh;
  const int t = threadIdx.x, w = t >> 6, lane = t & 63;
  const int mode = probe_mode((const u16*)Xv, t, &cnt_sh);
  // XCD swizzle: id in [0,512), xcd = id&7, p = id>>3; h = p>>2 (outer),
  // m-tile = xcd*4 + (p&3) (inner). Bijective since 512 % 8 == 0.
  const int id = blockIdx.y * 16 + blockIdx.x;
  const int xcd = id & 7, p = id >> 3;
  const int h = p >> 2;                   // head 0..15
  const int n0h = h * 64;
  const int m0 = ((xcd << 2) | (p & 3)) << 7;   // m-tile*128
  const int lr = lane & 15, lq = lane >> 4;
  f32x4 acc[3][2][4] = {};                // [e][m-half][mt]
  const int rA = t >> 2, cA = (t & 3) * 8;
  const int aoff0 = (m0 + rA) * 1024 + cA;
  const int aoff1 = (m0 + 64 + rA) * 1024 + cA;
  const int boff0 = (n0h + rA) * 1024 + cA;

  if (mode == 0) {
    const u16* Xp = (const u16*)Xv;
    const u16* Wp = (const u16*)Wv;
    // tile 0 -> regs -> buf0
    uint4 pa0 = *(const uint4*)(Xp + aoff0);
    uint4 pa1 = *(const uint4*)(Xp + aoff1);
    uint4 pb0 = *(const uint4*)(Wp + boff0);
    uint4 pb1 = *(const uint4*)(Wp + boff0 + 1048576);
    uint4 pb2 = *(const uint4*)(Wp + boff0 + 2097152);
    *(uint4*)&As[0][0][rA][cA] = pa0;
    *(uint4*)&As[0][1][rA][cA] = pa1;
    *(uint4*)&Bs[0][0][rA][cA] = pb0;
    *(uint4*)&Bs[0][1][rA][cA] = pb1;
    *(uint4*)&Bs[0][2][rA][cA] = pb2;
    // tile 1 -> regs
    pa0 = *(const uint4*)(Xp + aoff0 + 32);
    pa1 = *(const uint4*)(Xp + aoff1 + 32);
    pb0 = *(const uint4*)(Wp + boff0 + 32);
    pb1 = *(const uint4*)(Wp + boff0 + 1048576 + 32);
    pb2 = *(const uint4*)(Wp + boff0 + 2097152 + 32);
    __syncthreads();                      // buf0 visible, tile-1 regs resident
    int cur = 0;
    for (int k0 = 0; k0 < 1024; k0 += 32) {
      if (k0 + 32 < 1024) {               // write tile k+1 -> other buffer
        *(uint4*)&As[cur ^ 1][0][rA][cA] = pa0;
        *(uint4*)&As[cur ^ 1][1][rA][cA] = pa1;
        *(uint4*)&Bs[cur ^ 1][0][rA][cA] = pb0;
        *(uint4*)&Bs[cur ^ 1][1][rA][cA] = pb1;
        *(uint4*)&Bs[cur ^ 1][2][rA][cA] = pb2;
      }
      if (k0 + 64 < 1024) {               // prefetch tile k+2
        const int kn = k0 + 64;
        pa0 = *(const uint4*)(Xp + aoff0 + kn);
        pa1 = *(const uint4*)(Xp + aoff1 + kn);
        pb0 = *(const uint4*)(Wp + boff0 + kn);
        pb1 = *(const uint4*)(Wp + boff0 + 1048576 + kn);
        pb2 = *(const uint4*)(Wp + boff0 + 2097152 + kn);
      }
      bf16x8 bf[3];                       // compute from buf[cur]
#pragma unroll
      for (int e = 0; e < 3; ++e)
        bf[e] = *(const bf16x8*)&Bs[cur][e][(w << 4) + lr][lq * 8];
#pragma unroll
      for (int mt = 0; mt < 4; ++mt) {
        bf16x8 af0 = *(const bf16x8*)&As[cur][0][(mt << 4) + lr][lq * 8];
        bf16x8 af1 = *(const bf16x8*)&As[cur][1][(mt << 4) + lr][lq * 8];
#pragma unroll
        for (int e = 0; e < 3; ++e) {
          acc[e][0][mt] = __builtin_amdgcn_mfma_f32_16x16x32_bf16(af0, bf[e], acc[e][0][mt], 0, 0, 0);
          acc[e][1][mt] = __builtin_amdgcn_mfma_f32_16x16x32_bf16(af1, bf[e], acc[e][1][mt], 0, 0, 0);
        }
      }
      __syncthreads();                    // ONE barrier per step
      cur ^= 1;
    }
  } else {
    // fp32 fallback (dead in practice): single-buffer, 2-barrier
    for (int k0 = 0; k0 < 1024; k0 += 32) {
      __syncthreads();
      const float* Xf = (const float*)Xv;
      const float* Wf = (const float*)Wv;
#pragma unroll
      for (int ee = 0; ee < 8; ++ee) {
        As[0][0][rA][cA + ee] = f2b(Xf[aoff0 + k0 + ee]);
        As[0][1][rA][cA + ee] = f2b(Xf[aoff1 + k0 + ee]);
        Bs[0][0][rA][cA + ee] = f2b(Wf[boff0 + k0 + ee]);
        Bs[0][1][rA][cA + ee] = f2b(Wf[boff0 + 1048576 + k0 + ee]);
        Bs[0][2][rA][cA + ee] = f2b(Wf[boff0 + 2097152 + k0 + ee]);
      }
      __syncthreads();
      bf16x8 bf[3];
#pragma unroll
      for (int e = 0; e < 3; ++e)
        bf[e] = *(const bf16x8*)&Bs[0][e][(w << 4) + lr][lq * 8];
#pragma unroll
      for (int mt = 0; mt < 4; ++mt) {
        bf16x8 af0 = *(const bf16x8*)&As[0][0][(mt << 4) + lr][lq * 8];
        bf16x8 af1 = *(const bf16x8*)&As[0][1][(mt << 4) + lr][lq * 8];
#pragma unroll
        for (int e = 0; e < 3; ++e) {
          acc[e][0][mt] = __builtin_amdgcn_mfma_f32_16x16x32_bf16(af0, bf[e], acc[e][0][mt], 0, 0, 0);
          acc[e][1][mt] = __builtin_amdgcn_mfma_f32_16x16x32_bf16(af1, bf[e], acc[e][1][mt], 0, 0, 0);
        }
      }
    }
  }

  // epilogue: 6x Cs round-trip (R12-verbatim)
  for (int f = 0; f < 2; ++f) {
    const int m0f = m0 + f * 64;
    for (int e = 0; e < 3; ++e) {
      __syncthreads();
      {
        const int col = (w << 4) + lr;
#pragma unroll
        for (int mt = 0; mt < 4; ++mt)
#pragma unroll
          for (int i = 0; i < 4; ++i)
            Cs[mt * 16 + lq * 4 + i][col] = acc[e][f][mt][i];
      }
      __syncthreads();
      if (e == 2) {
        const int sx = t & 63, dh0 = (t >> 6) * 16;
        const int m = m0f + sx, b = m >> 11, s = m & 2047;
        const long hb = (long)(b * 16 + h) * 64;
#pragma unroll
        for (int u = 0; u < 16; ++u) {
          int dh = dh0 + u;
          Vo[(hb + dh) * 2048 + s] = f2b(Cs[sx][dh]);
        }
      } else {
        const int r = t >> 2, dh0 = (t & 3) * 16;
        const int m = m0f + r, b = m >> 11, s = m & 2047;
        const int obase = ((b * 16 + h) * 2048 + s) * 64;
        u16* O = (e == 0) ? Qo : Ko;
#pragma unroll
        for (int u = 0; u < 16; ++u) {
          int dh = dh0 + u;
          float v  = Cs[r][dh];
          float vp = Cs[r][dh ^ 32];
          float sign = (dh < 32) ? -1.0f : 1.0f;
          float fr  = __expf((float)(dh & 31) * -0.28782314f);
          float ang = (float)s * fr;
          float sn = __sinf(ang), cs = __cosf(ang);
          O[obase + dh] = f2b(v * cs + sign * vp * sn);
        }
      }
    }
  }
}

// ---------------------------------------------------------------------------
// Per-tile attention body (R9-proven math, factored; per-tile qt/state).
// ---------------------------------------------------------------------------
__device__ __forceinline__ void attn_tile(u16 QP[64][72], u16 Ks[64][72],
                                          u16 Vt[64][72], const bf16x8 qf[2],
                                          f32x4 o_acc[4], float& m_i, float& l_i,
                                          int kt, int qt_tile, int w, int lr,
                                          int lq, int lq4, int base16, int qrow_l) {
  f32x4 sa[4] = {};
#pragma unroll
  for (int mb = 0; mb < 4; ++mb)
#pragma unroll
    for (int kk = 0; kk < 2; ++kk) {
      bf16x8 kf = *(const bf16x8*)&Ks[mb * 16 + lr][kk * 32 + lq * 8];
      sa[mb] = __builtin_amdgcn_mfma_f32_16x16x32_bf16(kf, qf[kk], sa[mb], 0, 0, 0);
    }
  float sc[4][4];
  float m_new = m_i;
#pragma unroll
  for (int mb = 0; mb < 4; ++mb)
#pragma unroll
    for (int i = 0; i < 4; ++i) {
      float sv = sa[mb][i] * 0.125f;
      if (kt == qt_tile && (mb * 16 + lq4 + i) > qrow_l) sv = -3.0e4f;
      sc[mb][i] = sv;
      m_new = fmaxf(m_new, sv);
    }
  m_new = fmaxf(m_new, __shfl_xor(m_new, 16));
  m_new = fmaxf(m_new, __shfl_xor(m_new, 32));
  float alpha = __expf(m_i - m_new);
  m_i = m_new;
  float p[4][4], sm = 0.f;
#pragma unroll
  for (int mb = 0; mb < 4; ++mb)
#pragma unroll
    for (int i = 0; i < 4; ++i) { p[mb][i] = __expf(sc[mb][i] - m_new); sm += p[mb][i]; }
  sm += __shfl_xor(sm, 16);
  sm += __shfl_xor(sm, 32);
  l_i = l_i * alpha + sm;
#pragma unroll
  for (int mb = 0; mb < 4; ++mb) {
    uint2 pk;
    pk.x = (uint32_t)f2b(p[mb][0]) | ((uint32_t)f2b(p[mb][1]) << 16);
    pk.y = (uint32_t)f2b(p[mb][2]) | ((uint32_t)f2b(p[mb][3]) << 16);
    *(uint2*)&QP[w * 16 + lr][mb * 16 + lq4] = pk;
  }
#pragma unroll
  for (int i = 0; i < 4; ++i) {
    float ai = __shfl(alpha, base16 | (lq4 + i));
    o_acc[0][i] *= ai; o_acc[1][i] *= ai;
    o_acc[2][i] *= ai; o_acc[3][i] *= ai;
  }
  asm volatile("s_waitcnt lgkmcnt(0)" ::: "memory");
#pragma unroll
  for (int kk = 0; kk < 2; ++kk) {
    bf16x8 pf = *(const bf16x8*)&QP[w * 16 + lr][kk * 32 + lq * 8];
#pragma unroll
    for (int nb = 0; nb < 4; ++nb) {
      bf16x8 vf = *(const bf16x8*)&Vt[nb * 16 + lr][kk * 32 + lq * 8];
      o_acc[nb] = __builtin_amdgcn_mfma_f32_16x16x32_bf16(pf, vf, o_acc[nb], 0, 0, 0);
    }
  }
}

// ---------------------------------------------------------------------------
// Kernel 2: causal flash attention — R8-VERBATIM (R5 loop + T1 XCD remap).
// ---------------------------------------------------------------------------
__global__ __launch_bounds__(256) void k_attn(const u16* __restrict__ Q,
                                              const u16* __restrict__ K,
                                              const u16* __restrict__ V,
                                              u16* __restrict__ AO) {
  __shared__ u16 QP[64][72];
  __shared__ u16 Ks[2][64][72];
  __shared__ u16 Vt[2][64][72];
  // XCD swizzle: bijective (512 % 8 == 0). bh inner (4 per XCD), q-pair outer.
  const int id = blockIdx.y * 16 + blockIdx.x;
  const int xcd = id & 7, p = id >> 3;
  const int bh = (xcd << 2) | (p & 3);  // 4 bh per XCD
  const int qp = p >> 2;                // q-pair 0..15
  const int qtA = 31 - qp;              // 16..31
  const int qtB = qp;                   // 0..15  (qtB < qtA always)
  const int b = bh >> 4, h = bh & 15;
  const u16* Qg = Q + (bh * 2048) * 64;
  const u16* Kg = K + bh * 2048 * 64;
  const u16* Vg = V + (long)bh * 64 * 2048;
  const int t = threadIdx.x, w = t >> 6, lane = t & 63;
  const int lr = lane & 15, lq = lane >> 4;
  const int lq4 = lq * 4;
  const int base16 = lane & 48;
  const int r0 = t >> 3, c0 = (t & 7) * 8;
  const int qrow_l = w * 16 + lr;

  // kt=0 K/V loads issue first: overlap the Q staging below.
  uint4 pk0 = *(const uint4*)&Kg[r0 * 64 + c0];
  uint4 pk1 = *(const uint4*)&Kg[(r0 + 32) * 64 + c0];
  uint4 pv0 = *(const uint4*)&Vg[r0 * 2048 + c0];
  uint4 pv1 = *(const uint4*)&Vg[(r0 + 32) * 2048 + c0];

  bf16x8 qfA[2], qfB[2];
  *(uint4*)&QP[r0][c0]      = *(const uint4*)&Qg[(qtA * 64 + r0) * 64 + c0];
  *(uint4*)&QP[r0 + 32][c0] = *(const uint4*)&Qg[(qtA * 64 + r0 + 32) * 64 + c0];
  __syncthreads();
#pragma unroll
  for (int kk = 0; kk < 2; ++kk)
    qfA[kk] = *(const bf16x8*)&QP[w * 16 + lr][kk * 32 + lq * 8];
  __syncthreads();
  *(uint4*)&QP[r0][c0]      = *(const uint4*)&Qg[(qtB * 64 + r0) * 64 + c0];
  *(uint4*)&QP[r0 + 32][c0] = *(const uint4*)&Qg[(qtB * 64 + r0 + 32) * 64 + c0];
  __syncthreads();
#pragma unroll
  for (int kk = 0; kk < 2; ++kk)
    qfB[kk] = *(const bf16x8*)&QP[w * 16 + lr][kk * 32 + lq * 8];

  // tile 0 -> buf0; tile 1 -> regs (qtA >= 16 so tile 1 always exists)
  *(uint4*)&Ks[0][r0][c0]      = pk0;
  *(uint4*)&Ks[0][r0 + 32][c0] = pk1;
  *(uint4*)&Vt[0][r0][c0]      = pv0;
  *(uint4*)&Vt[0][r0 + 32][c0] = pv1;
  pk0 = *(const uint4*)&Kg[(64 + r0) * 64 + c0];
  pk1 = *(const uint4*)&Kg[(64 + r0 + 32) * 64 + c0];
  pv0 = *(const uint4*)&Vg[r0 * 2048 + 64 + c0];
  pv1 = *(const uint4*)&Vg[(r0 + 32) * 2048 + 64 + c0];
  __syncthreads();                      // buf0 visible everywhere

  float m_iA = -3.0e4f, l_iA = 0.f, m_iB = -3.0e4f, l_iB = 0.f;
  f32x4 o_accA[4] = {}, o_accB[4] = {};

  int cur = 0;
  for (int kt = 0; kt <= qtA; ++kt) {
    if (kt + 1 <= qtA) {                // write tile kt+1 -> other buffer
      *(uint4*)&Ks[cur ^ 1][r0][c0]      = pk0;
      *(uint4*)&Ks[cur ^ 1][r0 + 32][c0] = pk1;
      *(uint4*)&Vt[cur ^ 1][r0][c0]      = pv0;
      *(uint4*)&Vt[cur ^ 1][r0 + 32][c0] = pv1;
    }
    if (kt + 2 <= qtA) {                // prefetch tile kt+2
      const int kn = kt + 2;
      pk0 = *(const uint4*)&Kg[(kn * 64 + r0) * 64 + c0];
      pk1 = *(const uint4*)&Kg[(kn * 64 + r0 + 32) * 64 + c0];
      pv0 = *(const uint4*)&Vg[r0 * 2048 + kn * 64 + c0];
      pv1 = *(const uint4*)&Vg[(r0 + 32) * 2048 + kn * 64 + c0];
    }

    attn_tile(QP, Ks[cur], Vt[cur], qfA, o_accA, m_iA, l_iA, kt, qtA,
              w, lr, lq, lq4, base16, qrow_l);
    if (kt <= qtB) {
      asm volatile("s_waitcnt lgkmcnt(0)" ::: "memory");
      attn_tile(QP, Ks[cur], Vt[cur], qfB, o_accB, m_iB, l_iB, kt, qtB,
                w, lr, lq, lq4, base16, qrow_l);
    }
    __syncthreads();                    // ONE barrier per kt
    cur ^= 1;
  }
  float linvA = 1.0f / l_iA, linvB = 1.0f / l_iB;
#pragma unroll
  for (int i = 0; i < 4; ++i) {
    float invA = __shfl(linvA, base16 | (lq4 + i));
    float invB = __shfl(linvB, base16 | (lq4 + i));
    int rowA = qtA * 64 + w * 16 + lq4 + i;
    int rowB = qtB * 64 + w * 16 + lq4 + i;
    int obA = (b * 2048 + rowA) * 1024 + h * 64;
    int obB = (b * 2048 + rowB) * 1024 + h * 64;
#pragma unroll
    for (int nb = 0; nb < 4; ++nb) {
      AO[obA + nb * 16 + lr] = f2b(o_accA[nb][i] * invA);
      AO[obB + nb * 16 + lr] = f2b(o_accB[nb][i] * invB);
    }
  }
}

// ---------------------------------------------------------------------------
// Kernel 3: out = ao @ w_out^T. THIS ROUND: BK 32 -> 64 (16 K-steps instead
// of 32 — halves the fixed per-step barrier/drain cost that dominates this
// MFMA-thin kernel). LDS [64][64] linear rows (128B = exact bank wrap) with
// granule XOR swizzle on BOTH sides (rule #21): phys granule p holds logical
// p^(row&7); source pre-swizzled (l&7)^(l>>3), reads XOR (kk*4+lq)^(row&7).
// T1 XCD remap kept.
// ---------------------------------------------------------------------------
__global__ __launch_bounds__(256) void k_gemm_out(const u16* __restrict__ A,
                                                  const void* __restrict__ Bv,
                                                  void* __restrict__ Cv) {
  __shared__ u16 As[2][64][64];       // [buf]       16 KB
  __shared__ u16 Bs[2][2][64][64];    // [buf][half] 32 KB
  __shared__ int cnt_sh;
  const int t = threadIdx.x, w = t >> 6, lane = t & 63;
  const int mode = probe_mode((const u16*)Bv, t, &cnt_sh);
  // XCD swizzle: bijective (512 % 8 == 0). m inner (8 per XCD), n outer.
  const int id = blockIdx.y * 8 + blockIdx.x;
  const int xcd = id & 7, p = id >> 3;
  const int n0 = (p >> 3) * 128;
  const int m0 = ((xcd << 3) | (p & 7)) * 64;
  const int lr = lane & 15, lq = lane >> 4;
  f32x4 acc[2][4] = {};               // [n-half][mt]

  if (mode == 0) {
    const u16* Bp = (const u16*)Bv;
    // staging geometry: row = 64 u16 = 8 granules of 16B. Wave w stages
    // rows [w*8,w*8+8) and [w*8+32,w*8+40) of each 64-row tile. gload_lds
    // lane l -> row base+(l>>3), phys granule l&7; source granule is
    // pre-swizzled (l&7)^(l>>3)  [== (row&7)].
    const int lrow = lane >> 3;           // 0..7
    const int lg   = (lane & 7) ^ lrow;   // pre-swizzled source granule
    const long ar0 = (long)(m0 + w * 8 + lrow) * 1024 + lg * 8;
    const long ar1 = (long)(m0 + w * 8 + 32 + lrow) * 1024 + lg * 8;
    const long br00 = (long)(n0 + w * 8 + lrow) * 1024 + lg * 8;
    const long br01 = (long)(n0 + w * 8 + 32 + lrow) * 1024 + lg * 8;
    const long br10 = br00 + 65536;     // +64 rows of w_out (half 1)
    const long br11 = br01 + 65536;
#define STAGE_OUT(buf, kk)                                                     \
    do {                                                                       \
      GLOAD16(A + ar0 + (kk),   &As[buf][w * 8][0]);                           \
      GLOAD16(A + ar1 + (kk),   &As[buf][w * 8 + 32][0]);                      \
      GLOAD16(Bp + br00 + (kk), &Bs[buf][0][w * 8][0]);                        \
      GLOAD16(Bp + br01 + (kk), &Bs[buf][0][w * 8 + 32][0]);                   \
      GLOAD16(Bp + br10 + (kk), &Bs[buf][1][w * 8][0]);                        \
      GLOAD16(Bp + br11 + (kk), &Bs[buf][1][w * 8 + 32][0]);                   \
    } while (0)
    STAGE_OUT(0, 0);
    asm volatile("s_waitcnt vmcnt(0)" ::: "memory");
    __syncthreads();
    int cur = 0;
    for (int k0 = 0; k0 < 1024; k0 += 64) {
      if (k0 + 64 < 1024) STAGE_OUT(cur ^ 1, k0 + 64);
#pragma unroll
      for (int kk = 0; kk < 2; ++kk) {
        bf16x8 bfx[2];
        const int rowB = (w << 4) + lr;
        const int gB = ((kk * 4 + lq) ^ (rowB & 7)) * 8;
#pragma unroll
        for (int e = 0; e < 2; ++e)
          bfx[e] = *(const bf16x8*)&Bs[cur][e][rowB][gB];
#pragma unroll
        for (int mt = 0; mt < 4; ++mt) {
          const int rowA = (mt << 4) + lr;
          const int gA = ((kk * 4 + lq) ^ (rowA & 7)) * 8;
          bf16x8 af = *(const bf16x8*)&As[cur][rowA][gA];
#pragma unroll
          for (int e = 0; e < 2; ++e)
            acc[e][mt] = __builtin_amdgcn_mfma_f32_16x16x32_bf16(af, bfx[e], acc[e][mt], 0, 0, 0);
        }
      }
      __syncthreads();
      cur ^= 1;
    }
#undef STAGE_OUT
  } else {
    // fp32-W fallback (dead in practice): single-buffer, linear (no swizzle),
    // 2-barrier, BK=64. A is always bf16 (our ao buffer).
    const float* Bf = (const float*)Bv;
    const int r = t >> 2, cc = (t & 3) * 16;
    for (int k0 = 0; k0 < 1024; k0 += 64) {
      __syncthreads();
      *(uint4*)&As[0][r][cc]     = *(const uint4*)(A + (long)(m0 + r) * 1024 + k0 + cc);
      *(uint4*)&As[0][r][cc + 8] = *(const uint4*)(A + (long)(m0 + r) * 1024 + k0 + cc + 8);
#pragma unroll
      for (int ee = 0; ee < 16; ++ee) {
        Bs[0][0][r][cc + ee] = f2b(Bf[(long)(n0 + r) * 1024 + k0 + cc + ee]);
        Bs[0][1][r][cc + ee] = f2b(Bf[(long)(n0 + 64 + r) * 1024 + k0 + cc + ee]);
      }
      __syncthreads();
#pragma unroll
      for (int kk = 0; kk < 2; ++kk) {
        bf16x8 bfx[2];
        const int rowB = (w << 4) + lr;
#pragma unroll
        for (int e = 0; e < 2; ++e)
          bfx[e] = *(const bf16x8*)&Bs[0][e][rowB][kk * 32 + lq * 8];
#pragma unroll
        for (int mt = 0; mt < 4; ++mt) {
          bf16x8 af = *(const bf16x8*)&As[0][(mt << 4) + lr][kk * 32 + lq * 8];
#pragma unroll
          for (int e = 0; e < 2; ++e)
            acc[e][mt] = __builtin_amdgcn_mfma_f32_16x16x32_bf16(af, bfx[e], acc[e][mt], 0, 0, 0);
        }
      }
    }
  }
#pragma unroll
  for (int e = 0; e < 2; ++e) {
    const int col = n0 + e * 64 + (w << 4) + lr;
    if (mode == 0) {
      u16* C = (u16*)Cv;
#pragma unroll
      for (int mt = 0; mt < 4; ++mt)
#pragma unroll
        for (int i = 0; i < 4; ++i)
          C[(m0 + mt * 16 + lq * 4 + i) * 1024 + col] = f2b(acc[e][mt][i]);
    } else {
      float* C = (float*)Cv;
#pragma unroll
      for (int mt = 0; mt < 4; ++mt)
#pragma unroll
        for (int i = 0; i < 4; ++i)
          C[(m0 + mt * 16 + lq * 4 + i) * 1024 + col] = acc[e][mt][i];
    }
  }
}

// ---------------------------------------------------------------------------
extern "C" void kernel_launch(void* const* d_in, const int* in_sizes, int n_in,
                              void* d_out, int out_size, void* d_ws, size_t ws_size,
                              hipStream_t stream) {
  const void* x    = d_in[0];   // (4096,1024)
  const void* wqkv = d_in[1];   // (3072,1024)
  const void* wout = d_in[2];   // (1024,1024)

  // ws layout: [reserved 256B][q 8.39MB][k 8.39MB][v^T 8.39MB][ao]
  u16* qb = (u16*)((char*)d_ws + 256);
  u16* kb = qb + 4194304;
  u16* vb = kb + 4194304;
  u16* ao = vb + 4194304;

  k_qkv_rope<<<dim3(16, 32), 256, 0, stream>>>(x, wqkv, qb, kb, vb);
  k_attn    <<<dim3(16, 32), 256, 0, stream>>>(qb, kb, vb, ao);
  k_gemm_out<<<dim3(8, 64), 256, 0, stream>>>(ao, wout, d_out);
}